// Round 13
// baseline (476.812 us; speedup 1.0000x reference)
//
#include <hip/hip_runtime.h>

#define NN 60000
#define NE 300000
typedef unsigned short ush;

static inline int cdiv(int a, int b) { return (a + b - 1) / b; }

__device__ inline unsigned ord_enc(float x) {
  unsigned u = __float_as_uint(x);
  return (u & 0x80000000u) ? ~u : (u | 0x80000000u);
}
__device__ inline float ord_dec(unsigned u) {
  return __uint_as_float((u & 0x80000000u) ? (u & 0x7fffffffu) : ~u);
}
__device__ inline float bf2f(unsigned u16) { return __uint_as_float(u16 << 16); }
__device__ inline ush f2bf(float x) {
  unsigned u = __float_as_uint(x);
  return (ush)((u + 0x7FFFu + ((u >> 16) & 1u)) >> 16);
}
__device__ inline unsigned pack2(float lo, float hi) {
  return ((unsigned)f2bf(hi) << 16) | (unsigned)f2bf(lo);
}

// ================= CSR build (dst-sorted) =================
__global__ void deg_kernel(const int* __restrict__ key, int* __restrict__ deg) {
  int e = blockIdx.x * blockDim.x + threadIdx.x;
  if (e < NE) atomicAdd(deg + key[e], 1);
}

__global__ void scan1_kernel(const int* __restrict__ deg, int* __restrict__ rowptr,
                             int* __restrict__ partial) {
  __shared__ int s[256];
  int i = blockIdx.x * 256 + threadIdx.x;
  int v = (i < NN) ? deg[i] : 0;
  s[threadIdx.x] = v;
  __syncthreads();
  for (int off = 1; off < 256; off <<= 1) {
    int t = (threadIdx.x >= off) ? s[threadIdx.x - off] : 0;
    __syncthreads();
    s[threadIdx.x] += t;
    __syncthreads();
  }
  if (i < NN) rowptr[i] = s[threadIdx.x] - v;
  if (threadIdx.x == 255) partial[blockIdx.x] = s[255];
}

__global__ void scan2_kernel(int* __restrict__ partial, int nb) {
  __shared__ int s[256];
  int v = (threadIdx.x < nb) ? partial[threadIdx.x] : 0;
  s[threadIdx.x] = v;
  __syncthreads();
  for (int off = 1; off < 256; off <<= 1) {
    int t = (threadIdx.x >= off) ? s[threadIdx.x - off] : 0;
    __syncthreads();
    s[threadIdx.x] += t;
    __syncthreads();
  }
  if (threadIdx.x < nb) partial[threadIdx.x] = s[threadIdx.x] - v;
}

__global__ void scan3_kernel(int* __restrict__ rowptr, const int* __restrict__ partial,
                             int* __restrict__ cursor) {
  int i = blockIdx.x * 256 + threadIdx.x;
  if (i < NN) {
    int r = rowptr[i] + partial[blockIdx.x];
    rowptr[i] = r;
    cursor[i] = r;
  }
}

__global__ void scatter_dst_kernel(const int* __restrict__ src, const int* __restrict__ dst,
                                   int* __restrict__ cursor, int* __restrict__ src_s,
                                   int* __restrict__ dst_s, int* __restrict__ eid_s) {
  int e = blockIdx.x * blockDim.x + threadIdx.x;
  if (e >= NE) return;
  int d = dst[e];
  int j = atomicAdd(cursor + d, 1);
  src_s[j] = src[e];
  dst_s[j] = d;
  eid_s[j] = e;
}

// permute ef rows into dst-sorted order (sequential write, gathered read)
__global__ void permute_ef_kernel(const float* __restrict__ ef, const int* __restrict__ eid_s,
                                  float* __restrict__ ef_s) {
  int j = blockIdx.x * blockDim.x + threadIdx.x;
  if (j >= NE * 4) return;
  int slot = j >> 2, c = j & 3;
  int e = eid_s[slot];
  ((float4*)ef_s)[(size_t)slot * 4 + c] = ((const float4*)ef)[(size_t)e * 4 + c];
}

// ---------------- fold: precompute folded weight products (7424 dots of length 64) -------
__global__ void fold_kernel(const float* __restrict__ fp_w, const float* __restrict__ fp_b,
                            const float* __restrict__ ep_w, const float* __restrict__ ep_b,
                            const float* __restrict__ fij, const float* __restrict__ ebias,
                            const float* __restrict__ ni, const float* __restrict__ nj,
                            const float* __restrict__ node, float* __restrict__ fold) {
  int t = blockIdx.x * blockDim.x + threadIdx.x;
  if (t >= 7424) return;
  int o = t & 63;
  const float* A;
  const float* B;
  float init = 0.f;
  if (t < 1024)      { A = ep_w + (size_t)(t >> 6) * 64; B = fij + o; }
  else if (t < 1088) { A = ep_b; B = fij + o; init = ebias[o]; }
  else if (t < 3136) { A = fp_w + (size_t)((t - 1088) >> 6) * 64; B = ni + o; }
  else if (t < 5184) { A = fp_w + (size_t)((t - 3136) >> 6) * 64; B = nj + o; }
  else if (t < 7232) { A = fp_w + (size_t)((t - 5184) >> 6) * 64; B = node + o; }
  else if (t < 7296) { A = fp_b; B = ni + o; }
  else if (t < 7360) { A = fp_b; B = nj + o; }
  else               { A = fp_b; B = node + o; }
  float a = init;
  for (int i = 0; i < 64; ++i) a = fmaf(A[i], B[(size_t)i * 64], a);
  fold[t] = a;
}

// ---------------- pack nn_w/nn_b into bf16 W2bf[544][32]: row c=k*32+i -> nn_w[k][i*32+o],
//                  rows 512+i -> nn_b[i*32+o] ----------------
__global__ void nnwt_kernel(const float* __restrict__ nn_w, const float* __restrict__ nn_b,
                            ush* __restrict__ W2bf) {
  int t = blockIdx.x * blockDim.x + threadIdx.x;
  if (t >= 544 * 32) return;
  int c = t >> 5, o = t & 31;
  float v;
  if (c < 512) {
    int k = c >> 5, i = c & 31;
    v = nn_w[(size_t)k * 1024 + i * 32 + o];
  } else {
    v = nn_b[(c - 512) * 32 + o];
  }
  W2bf[t] = f2bf(v);
}

// ---------------- tiled GEMM (rows x K) @ (K x 64) -> bf16 out; 3 weight sets ------------
template <int K, bool BIAS>
__global__ __launch_bounds__(256, 2) void gemm3_kernel(
    const float* __restrict__ A, const float* __restrict__ W0, const float* __restrict__ W1,
    const float* __restrict__ W2, const float* __restrict__ b0, const float* __restrict__ b1,
    const float* __restrict__ b2, ush* __restrict__ o0, ush* __restrict__ o1,
    ush* __restrict__ o2, int rows) {
  __shared__ float sA[128][K + 1];
  __shared__ float sW[K][64];
  const float* W = blockIdx.y == 0 ? W0 : blockIdx.y == 1 ? W1 : W2;
  const float* bb = blockIdx.y == 0 ? b0 : blockIdx.y == 1 ? b1 : b2;
  ush* out = blockIdx.y == 0 ? o0 : blockIdx.y == 1 ? o1 : o2;
  int t = threadIdx.x;
  int r0 = blockIdx.x * 128;
  for (int i = t; i < K * 16; i += 256) ((float4*)sW)[i] = ((const float4*)W)[i];
  for (int i = t; i < 128 * (K / 4); i += 256) {
    int rr = i / (K / 4), cc = i % (K / 4);
    float4 v = (r0 + rr < rows) ? ((const float4*)(A + (size_t)(r0 + rr) * K))[cc]
                                : make_float4(0.f, 0.f, 0.f, 0.f);
    sA[rr][cc * 4 + 0] = v.x;
    sA[rr][cc * 4 + 1] = v.y;
    sA[rr][cc * 4 + 2] = v.z;
    sA[rr][cc * 4 + 3] = v.w;
  }
  __syncthreads();
  int rg = t >> 3, cg = t & 7;
  float acc[4][8];
#pragma unroll
  for (int i = 0; i < 4; ++i)
#pragma unroll
    for (int j = 0; j < 8; ++j) acc[i][j] = 0.f;
#pragma unroll 8
  for (int k = 0; k < K; ++k) {
    float a0 = sA[rg * 4 + 0][k], a1 = sA[rg * 4 + 1][k];
    float a2 = sA[rg * 4 + 2][k], a3 = sA[rg * 4 + 3][k];
    float4 wA = *(const float4*)&sW[k][cg * 8];
    float4 wB = *(const float4*)&sW[k][cg * 8 + 4];
#pragma unroll
    for (int i = 0; i < 4; ++i) {
      float a = i == 0 ? a0 : i == 1 ? a1 : i == 2 ? a2 : a3;
      acc[i][0] = fmaf(a, wA.x, acc[i][0]); acc[i][1] = fmaf(a, wA.y, acc[i][1]);
      acc[i][2] = fmaf(a, wA.z, acc[i][2]); acc[i][3] = fmaf(a, wA.w, acc[i][3]);
      acc[i][4] = fmaf(a, wB.x, acc[i][4]); acc[i][5] = fmaf(a, wB.y, acc[i][5]);
      acc[i][6] = fmaf(a, wB.z, acc[i][6]); acc[i][7] = fmaf(a, wB.w, acc[i][7]);
    }
  }
  float bv[8];
#pragma unroll
  for (int j = 0; j < 8; ++j) bv[j] = BIAS ? bb[cg * 8 + j] : 0.f;
#pragma unroll
  for (int i = 0; i < 4; ++i) {
    int r = r0 + rg * 4 + i;
    if (r < rows) {
      uint4 pv;
      pv.x = pack2(acc[i][0] + bv[0], acc[i][1] + bv[1]);
      pv.y = pack2(acc[i][2] + bv[2], acc[i][3] + bv[3]);
      pv.z = pack2(acc[i][4] + bv[4], acc[i][5] + bv[5]);
      pv.w = pack2(acc[i][6] + bv[6], acc[i][7] + bv[7]);
      *(uint4*)(out + (size_t)r * 64 + cg * 8) = pv;
    }
  }
}

// ---------------- edge GEMM + fused f_out epilogue (edges in dst-sorted order) -----------
template <int K, bool STORE, bool ABF>
__global__ __launch_bounds__(256, 2) void gemm_fout_kernel(
    const void* __restrict__ Ap, const float* __restrict__ W, const float* __restrict__ bias,
    const ush* __restrict__ hs, const ush* __restrict__ hd, const int* __restrict__ src_s,
    const int* __restrict__ dst_s, const float* __restrict__ attn, ush* __restrict__ fstore,
    float* __restrict__ logit) {
  __shared__ float sA[128][K + 1];
  __shared__ float sW[K][64];
  int t = threadIdx.x;
  int r0 = blockIdx.x * 128;
  for (int i = t; i < K * 16; i += 256) ((float4*)sW)[i] = ((const float4*)W)[i];
  if (ABF) {
    const ush* A = (const ush*)Ap;
    for (int i = t; i < 128 * (K / 8); i += 256) {
      int rr = i / (K / 8), cc = i % (K / 8);
      uint4 v = (r0 + rr < NE) ? ((const uint4*)(A + (size_t)(r0 + rr) * K))[cc]
                               : make_uint4(0, 0, 0, 0);
      float* dp = &sA[rr][cc * 8];
      dp[0] = bf2f(v.x & 0xffff); dp[1] = bf2f(v.x >> 16);
      dp[2] = bf2f(v.y & 0xffff); dp[3] = bf2f(v.y >> 16);
      dp[4] = bf2f(v.z & 0xffff); dp[5] = bf2f(v.z >> 16);
      dp[6] = bf2f(v.w & 0xffff); dp[7] = bf2f(v.w >> 16);
    }
  } else {
    const float* A = (const float*)Ap;
    for (int i = t; i < 128 * (K / 4); i += 256) {
      int rr = i / (K / 4), cc = i % (K / 4);
      float4 v = (r0 + rr < NE) ? ((const float4*)(A + (size_t)(r0 + rr) * K))[cc]
                                : make_float4(0.f, 0.f, 0.f, 0.f);
      sA[rr][cc * 4 + 0] = v.x;
      sA[rr][cc * 4 + 1] = v.y;
      sA[rr][cc * 4 + 2] = v.z;
      sA[rr][cc * 4 + 3] = v.w;
    }
  }
  __syncthreads();
  int rg = t >> 3, cg = t & 7;
  float acc[4][8];
#pragma unroll
  for (int i = 0; i < 4; ++i)
#pragma unroll
    for (int j = 0; j < 8; ++j) acc[i][j] = 0.f;
#pragma unroll 8
  for (int k = 0; k < K; ++k) {
    float a0 = sA[rg * 4 + 0][k], a1 = sA[rg * 4 + 1][k];
    float a2 = sA[rg * 4 + 2][k], a3 = sA[rg * 4 + 3][k];
    float4 wA = *(const float4*)&sW[k][cg * 8];
    float4 wB = *(const float4*)&sW[k][cg * 8 + 4];
#pragma unroll
    for (int i = 0; i < 4; ++i) {
      float a = i == 0 ? a0 : i == 1 ? a1 : i == 2 ? a2 : a3;
      acc[i][0] = fmaf(a, wA.x, acc[i][0]); acc[i][1] = fmaf(a, wA.y, acc[i][1]);
      acc[i][2] = fmaf(a, wA.z, acc[i][2]); acc[i][3] = fmaf(a, wA.w, acc[i][3]);
      acc[i][4] = fmaf(a, wB.x, acc[i][4]); acc[i][5] = fmaf(a, wB.y, acc[i][5]);
      acc[i][6] = fmaf(a, wB.z, acc[i][6]); acc[i][7] = fmaf(a, wB.w, acc[i][7]);
    }
  }
  float bv[8], av[8];
#pragma unroll
  for (int j = 0; j < 8; ++j) {
    bv[j] = bias[cg * 8 + j];
    av[j] = attn[cg * 8 + j];
  }
#pragma unroll
  for (int i = 0; i < 4; ++i) {
    int r = r0 + rg * 4 + i;
    if (r < NE) {
      int s = src_s[r], d = dst_s[r];
      uint4 hv = *(const uint4*)(hs + (size_t)s * 64 + cg * 8);
      uint4 dv = *(const uint4*)(hd + (size_t)d * 64 + cg * 8);
      float fo[8];
      fo[0] = acc[i][0] + bf2f(hv.x & 0xffff) + bf2f(dv.x & 0xffff) + bv[0];
      fo[1] = acc[i][1] + bf2f(hv.x >> 16)    + bf2f(dv.x >> 16)    + bv[1];
      fo[2] = acc[i][2] + bf2f(hv.y & 0xffff) + bf2f(dv.y & 0xffff) + bv[2];
      fo[3] = acc[i][3] + bf2f(hv.y >> 16)    + bf2f(dv.y >> 16)    + bv[3];
      fo[4] = acc[i][4] + bf2f(hv.z & 0xffff) + bf2f(dv.z & 0xffff) + bv[4];
      fo[5] = acc[i][5] + bf2f(hv.z >> 16)    + bf2f(dv.z >> 16)    + bv[5];
      fo[6] = acc[i][6] + bf2f(hv.w & 0xffff) + bf2f(dv.w & 0xffff) + bv[6];
      fo[7] = acc[i][7] + bf2f(hv.w >> 16)    + bf2f(dv.w >> 16)    + bv[7];
      float p = 0.f;
#pragma unroll
      for (int j = 0; j < 8; ++j) {
        fo[j] = fo[j] >= 0.f ? fo[j] : 0.01f * fo[j];  // LeakyReLU
        p = fmaf(fo[j], av[j], p);
      }
      if (STORE) {
        uint4 pv;
        pv.x = pack2(fo[0], fo[1]);
        pv.y = pack2(fo[2], fo[3]);
        pv.z = pack2(fo[4], fo[5]);
        pv.w = pack2(fo[6], fo[7]);
        *(uint4*)(fstore + (size_t)r * 64 + cg * 8) = pv;
      }
      p += __shfl_xor(p, 1, 64);
      p += __shfl_xor(p, 2, 64);
      p += __shfl_xor(p, 4, 64);
      if (cg == 0) logit[r] = p;
    }
  }
}

// ---------------- EGAT: gather-aggregate, 4-deep load-then-FMA pipeline ------------------
__global__ __launch_bounds__(256, 4) void agg_gather_kernel(
    const ush* __restrict__ hn, const float* __restrict__ logit, const int* __restrict__ rowptr,
    const int* __restrict__ deg, const int* __restrict__ src_s, float* __restrict__ hnew) {
  int wave = (blockIdx.x * blockDim.x + threadIdx.x) >> 6;
  int lane = threadIdx.x & 63;
  if (wave >= NN) return;
  int n = wave, d = deg[n], r0 = rowptr[n];
  if (d == 0) {
    hnew[(size_t)n * 64 + lane] = 0.f;
    return;
  }
  float m = -3.0e38f;
  for (int j = 0; j < d; ++j) m = fmaxf(m, logit[r0 + j]);
  float sum = 0.f, acc0 = 0.f, acc1 = 0.f, acc2 = 0.f, acc3 = 0.f;
  int j = 0;
  for (; j + 3 < d; j += 4) {
    int jj = r0 + j;
    int s0 = src_s[jj + 0], s1 = src_s[jj + 1], s2 = src_s[jj + 2], s3 = src_s[jj + 3];
    float l0 = logit[jj + 0], l1 = logit[jj + 1], l2 = logit[jj + 2], l3 = logit[jj + 3];
    ush h0 = hn[(size_t)s0 * 64 + lane];
    ush h1 = hn[(size_t)s1 * 64 + lane];
    ush h2 = hn[(size_t)s2 * 64 + lane];
    ush h3 = hn[(size_t)s3 * 64 + lane];
    float w0 = __expf(l0 - m), w1 = __expf(l1 - m);
    float w2 = __expf(l2 - m), w3 = __expf(l3 - m);
    sum += (w0 + w1) + (w2 + w3);
    acc0 = fmaf(w0, bf2f(h0), acc0);
    acc1 = fmaf(w1, bf2f(h1), acc1);
    acc2 = fmaf(w2, bf2f(h2), acc2);
    acc3 = fmaf(w3, bf2f(h3), acc3);
  }
  for (; j < d; ++j) {
    int jj = r0 + j;
    float w = __expf(logit[jj] - m);
    sum += w;
    acc0 = fmaf(w, bf2f(hn[(size_t)src_s[jj] * 64 + lane]), acc0);
  }
  hnew[(size_t)n * 64 + lane] = ((acc0 + acc1) + (acc2 + acc3)) / sum;
}

// ---------------- NNConv fused: per-node outer-product accumulate + 544-dot epilogue -----
// sArr[n][o] = sum_{k,i} G[k][i]*nn_w[k][i][o] + sum_i Fsum[i]*nn_b[i][o],
// G[k][i] = sum_{e->n} ef[e][k]*face[src_e][i]; Fsum[i] = sum_{e->n} face[src_e][i].
// lane = k4*4+ib: owns k=k4=lane>>2, i in [ib*8, ib*8+8). Only face (7.7MB, L2-hot) gathered.
__global__ __launch_bounds__(256, 3) void nnconv_fused_kernel(
    const float* __restrict__ face, const float* __restrict__ ef_s, const ush* __restrict__ W2bf,
    const int* __restrict__ rowptr, const int* __restrict__ deg, const int* __restrict__ src_s,
    float* __restrict__ sArr) {
  __shared__ ush sW[544 * 32];    // 34816 B
  __shared__ float sG[4][544];    // 8704 B
  // stage W2bf (before any early return)
  for (int i = threadIdx.x; i < 544 * 32 / 8; i += 256)
    ((uint4*)sW)[i] = ((const uint4*)W2bf)[i];
  __syncthreads();
  int wave = (blockIdx.x * blockDim.x + threadIdx.x) >> 6;
  int lane = threadIdx.x & 63;
  if (wave >= NN) return;
  int n = wave, d = deg[n], r0 = rowptr[n];
  int k4 = lane >> 2, ib = lane & 3;
  int ws = threadIdx.x >> 6;
  float G[8];
#pragma unroll
  for (int j = 0; j < 8; ++j) G[j] = 0.f;
  float fs[8];
#pragma unroll
  for (int j = 0; j < 8; ++j) fs[j] = 0.f;
  int j = 0;
  for (; j + 1 < d; j += 2) {
    int jj = r0 + j;
    int s0 = src_s[jj], s1 = src_s[jj + 1];
    const float4* fp0 = (const float4*)(face + (size_t)s0 * 32 + ib * 8);
    const float4* fp1 = (const float4*)(face + (size_t)s1 * 32 + ib * 8);
    float4 fa0 = fp0[0], fb0 = fp0[1];
    float4 fa1 = fp1[0], fb1 = fp1[1];
    float ev0 = ef_s[(size_t)jj * 16 + k4];
    float ev1 = ef_s[(size_t)(jj + 1) * 16 + k4];
    G[0] = fmaf(ev0, fa0.x, G[0]); G[1] = fmaf(ev0, fa0.y, G[1]);
    G[2] = fmaf(ev0, fa0.z, G[2]); G[3] = fmaf(ev0, fa0.w, G[3]);
    G[4] = fmaf(ev0, fb0.x, G[4]); G[5] = fmaf(ev0, fb0.y, G[5]);
    G[6] = fmaf(ev0, fb0.z, G[6]); G[7] = fmaf(ev0, fb0.w, G[7]);
    G[0] = fmaf(ev1, fa1.x, G[0]); G[1] = fmaf(ev1, fa1.y, G[1]);
    G[2] = fmaf(ev1, fa1.z, G[2]); G[3] = fmaf(ev1, fa1.w, G[3]);
    G[4] = fmaf(ev1, fb1.x, G[4]); G[5] = fmaf(ev1, fb1.y, G[5]);
    G[6] = fmaf(ev1, fb1.z, G[6]); G[7] = fmaf(ev1, fb1.w, G[7]);
    if (k4 == 0) {
      fs[0] += fa0.x + fa1.x; fs[1] += fa0.y + fa1.y;
      fs[2] += fa0.z + fa1.z; fs[3] += fa0.w + fa1.w;
      fs[4] += fb0.x + fb1.x; fs[5] += fb0.y + fb1.y;
      fs[6] += fb0.z + fb1.z; fs[7] += fb0.w + fb1.w;
    }
  }
  if (j < d) {
    int jj = r0 + j;
    int s0 = src_s[jj];
    const float4* fp0 = (const float4*)(face + (size_t)s0 * 32 + ib * 8);
    float4 fa0 = fp0[0], fb0 = fp0[1];
    float ev0 = ef_s[(size_t)jj * 16 + k4];
    G[0] = fmaf(ev0, fa0.x, G[0]); G[1] = fmaf(ev0, fa0.y, G[1]);
    G[2] = fmaf(ev0, fa0.z, G[2]); G[3] = fmaf(ev0, fa0.w, G[3]);
    G[4] = fmaf(ev0, fb0.x, G[4]); G[5] = fmaf(ev0, fb0.y, G[5]);
    G[6] = fmaf(ev0, fb0.z, G[6]); G[7] = fmaf(ev0, fb0.w, G[7]);
    if (k4 == 0) {
      fs[0] += fa0.x; fs[1] += fa0.y; fs[2] += fa0.z; fs[3] += fa0.w;
      fs[4] += fb0.x; fs[5] += fb0.y; fs[6] += fb0.z; fs[7] += fb0.w;
    }
  }
  // stage G into per-wave LDS: c = k4*32 + ib*8 + j; Fsum at 512 + ib*8 + j (lanes 0-3)
  {
    int cbase = k4 * 32 + ib * 8;
#pragma unroll
    for (int u = 0; u < 8; ++u) sG[ws][cbase + u] = G[u];
    if (k4 == 0) {
#pragma unroll
      for (int u = 0; u < 8; ++u) sG[ws][512 + ib * 8 + u] = fs[u];
    }
  }
  __threadfence_block();  // order LDS writes before reads (wave-local)
  // epilogue: o = lane&31; halves split the 544-dot, combine via shfl_xor(32)
  int o = lane & 31;
  int cbase = (lane >> 5) * 272;
  float acc = 0.f;
#pragma unroll 8
  for (int c = 0; c < 272; ++c) {
    float gv = sG[ws][cbase + c];
    float wv = bf2f(sW[(size_t)(cbase + c) * 32 + o]);
    acc = fmaf(gv, wv, acc);
  }
  acc += __shfl_xor(acc, 32, 64);
  if (lane < 32) sArr[(size_t)n * 32 + o] = acc;
}

// ---------------- combine node_features + gate logit (fused; wave per node) --------------
__global__ void combine_gate_kernel(const float* __restrict__ hfin, const float* __restrict__ sArr,
                                    const int* __restrict__ deg, const float* __restrict__ nn_bias,
                                    const float* __restrict__ gate_w, const float* __restrict__ gate_b,
                                    float* __restrict__ out, float* __restrict__ g) {
  int wave = (blockIdx.x * blockDim.x + threadIdx.x) >> 6;
  int lane = threadIdx.x & 63;
  if (wave >= NN) return;
  int n = wave;
  float v0 = hfin[(size_t)n * 64 + lane];
  int c1 = lane + 64;
  float v1 = (c1 < 96)
                 ? sArr[(size_t)n * 32 + (c1 - 64)] / fmaxf((float)deg[n], 1.0f) + nn_bias[c1 - 64]
                 : 0.f;
  out[(size_t)n * 128 + lane] = v0;
  out[(size_t)n * 128 + c1] = v1;
  float p = v0 * gate_w[lane] + ((c1 < 96) ? v1 * gate_w[c1] : 0.f);
#pragma unroll
  for (int off = 32; off; off >>= 1) p += __shfl_xor(p, off, 64);
  if (lane == 0) g[n] = p + gate_b[0];
}

// ---------------- max over g (block-reduced, 1 atomic per block) ----------------
__global__ void gate_max_kernel(const float* __restrict__ g, unsigned* __restrict__ gmax) {
  int tid = blockIdx.x * blockDim.x + threadIdx.x;
  int stride = gridDim.x * blockDim.x;
  float v = -3.0e38f;
  for (int n = tid; n < NN; n += stride) v = fmaxf(v, g[n]);
#pragma unroll
  for (int off = 32; off; off >>= 1) v = fmaxf(v, __shfl_xor(v, off, 64));
  __shared__ float sm[4];
  int lane = threadIdx.x & 63, wid = threadIdx.x >> 6;
  if (lane == 0) sm[wid] = v;
  __syncthreads();
  if (threadIdx.x == 0) {
    float m = fmaxf(fmaxf(sm[0], sm[1]), fmaxf(sm[2], sm[3]));
    atomicMax(gmax, ord_enc(m));
  }
}

// ---------------- pooling: exp + weighted accumulate (fused) ----------------
__global__ void pool_exp_kernel(const float* __restrict__ nf, const float* __restrict__ g,
                                const unsigned* __restrict__ gmax, float* __restrict__ gacc,
                                float* __restrict__ gsum) {
  int o = threadIdx.x;  // blockDim = 128
  float m = ord_dec(*gmax);
  float acc = 0.f, ws = 0.f;
  for (int n = blockIdx.x; n < NN; n += gridDim.x) {
    float w = __expf(g[n] - m);
    ws += w;
    acc += w * nf[(size_t)n * 128 + o];
  }
  atomicAdd(gacc + o, acc);
  if (o == 0) atomicAdd(gsum, ws);
}

__global__ void finalize_kernel(const float* __restrict__ gacc, const float* __restrict__ gsum,
                                float* __restrict__ out) {
  int o = threadIdx.x;
  if (o < 128) out[(size_t)NN * 128 + o] = gacc[o] / gsum[0];
}

extern "C" void kernel_launch(void* const* d_in, const int* in_sizes, int n_in,
                              void* d_out, int out_size, void* d_ws, size_t ws_size,
                              hipStream_t stream) {
  const float* face    = (const float*)d_in[0];
  const float* ef      = (const float*)d_in[1];
  const float* fp_w    = (const float*)d_in[2];
  const float* fp_b    = (const float*)d_in[3];
  const float* ep_w    = (const float*)d_in[4];
  const float* ep_b    = (const float*)d_in[5];
  const float* nn_w    = (const float*)d_in[6];
  const float* nn_b    = (const float*)d_in[7];
  const float* nn_bias = (const float*)d_in[8];
  const float* gate_w  = (const float*)d_in[9];
  const float* gate_b  = (const float*)d_in[10];
  const int*   src     = (const int*)d_in[11];
  const int*   dst     = (const int*)d_in[12];
  const float* e1_attn = (const float*)d_in[17];
  const float* e2_ni   = (const float*)d_in[19];
  const float* e2_nj   = (const float*)d_in[20];
  const float* e2_fij  = (const float*)d_in[21];
  const float* e2_node = (const float*)d_in[22];
  const float* e2_attn = (const float*)d_in[23];
  const float* e2_bias = (const float*)d_in[24];
  float* out = (float*)d_out;

  char* p = (char*)d_ws;
  auto alloc = [&](size_t nfloats) {
    float* r = (float*)p;
    p += ((nfloats * 4 + 255) / 256) * 256;
    return r;
  };
  float* h0 = alloc((size_t)NN * 64);   // layer-2 output
  float* h1 = alloc((size_t)NN * 64);   // layer-1 output
  ush* hs16 = (ush*)alloc((size_t)NN * 32);   // NN*64 bf16
  ush* hd16 = (ush*)alloc((size_t)NN * 32);
  ush* hn16 = (ush*)alloc((size_t)NN * 32);
  ush* f116 = (ush*)alloc((size_t)NE * 32);   // NE*64 bf16 (dst-sorted order)
  float* logit = alloc(NE);                   // dst-sorted order
  float* sArr  = alloc((size_t)NN * 32);
  float* g     = alloc(NN);
  float* gacc  = alloc(128);
  float* gsum  = alloc(1);
  unsigned* gmax = (unsigned*)alloc(1);
  float* fold  = alloc(7424);
  ush* W2bf    = (ush*)alloc(544 * 16);       // 544*32 bf16
  // dst-CSR
  int* deg    = (int*)alloc(NN);
  int* rowptr = (int*)alloc(NN);
  int* cursor = (int*)alloc(NN);
  int* partial = (int*)alloc(256);
  int* src_s  = (int*)alloc(NE);
  int* dst_s  = (int*)alloc(NE);
  int* eid_s  = (int*)alloc(NE);
  float* ef_s = alloc((size_t)NE * 16);       // permuted edge features

  const float* Wf1  = fold;
  const float* b1f  = fold + 1024;
  const float* Wni1 = fold + 1088;
  const float* Wnj1 = fold + 3136;
  const float* Wno1 = fold + 5184;
  const float* bni1 = fold + 7232;
  const float* bnj1 = fold + 7296;
  const float* bno1 = fold + 7360;

  const int B = 256;
  const int NGB = cdiv(NN, 128);
  const int EGB = cdiv(NE, 128);
  const int NB256 = cdiv(NN, 256);

  // ---- CSR build (dst-sorted) + edge permutation ----
  hipMemsetAsync(deg, 0, NN * 4, stream);
  deg_kernel<<<cdiv(NE, B), B, 0, stream>>>(dst, deg);
  scan1_kernel<<<NB256, 256, 0, stream>>>(deg, rowptr, partial);
  scan2_kernel<<<1, 256, 0, stream>>>(partial, NB256);
  scan3_kernel<<<NB256, 256, 0, stream>>>(rowptr, partial, cursor);
  scatter_dst_kernel<<<cdiv(NE, B), B, 0, stream>>>(src, dst, cursor, src_s, dst_s, eid_s);
  permute_ef_kernel<<<cdiv(NE * 4, B), B, 0, stream>>>(ef, eid_s, ef_s);

  // folded weights + nn weight pack (tiny)
  fold_kernel<<<29, B, 0, stream>>>(fp_w, fp_b, ep_w, ep_b,
                                    (const float*)d_in[15], (const float*)d_in[18],
                                    (const float*)d_in[13], (const float*)d_in[14],
                                    (const float*)d_in[16], fold);
  nnwt_kernel<<<68, B, 0, stream>>>(nn_w, nn_b, W2bf);

  // ---- EGAT layer 1 (edges processed in dst-sorted order) ----
  gemm3_kernel<32, true><<<dim3(NGB, 3), B, 0, stream>>>(face, Wni1, Wnj1, Wno1, bni1, bnj1,
                                                         bno1, hs16, hd16, hn16, NN);
  gemm_fout_kernel<16, true, false><<<EGB, B, 0, stream>>>(ef_s, Wf1, b1f, hs16, hd16, src_s,
                                                           dst_s, e1_attn, f116, logit);
  agg_gather_kernel<<<cdiv(NN * 64, B), B, 0, stream>>>(hn16, logit, rowptr, deg, src_s, h1);

  // ---- EGAT layer 2 ----
  gemm3_kernel<64, false><<<dim3(NGB, 3), B, 0, stream>>>(h1, e2_ni, e2_nj, e2_node, nullptr,
                                                          nullptr, nullptr, hs16, hd16, hn16, NN);
  gemm_fout_kernel<64, false, true><<<EGB, B, 0, stream>>>(f116, e2_fij, e2_bias, hs16, hd16,
                                                           src_s, dst_s, e2_attn, nullptr, logit);
  agg_gather_kernel<<<cdiv(NN * 64, B), B, 0, stream>>>(hn16, logit, rowptr, deg, src_s, h0);

  // ---- NNConv (fused outer-product form; only face gathered, z eliminated) ----
  nnconv_fused_kernel<<<cdiv(NN * 64, B), B, 0, stream>>>(face, ef_s, W2bf, rowptr, deg,
                                                          src_s, sArr);

  // ---- combine node features + gate logits ----
  hipMemsetAsync(gacc, 0, 128 * 4, stream);
  hipMemsetAsync(gsum, 0, 4, stream);
  hipMemsetAsync(gmax, 0, 4, stream);
  combine_gate_kernel<<<cdiv(NN * 64, B), B, 0, stream>>>(h0, sArr, deg, nn_bias, gate_w,
                                                          gate_b, out, g);
  gate_max_kernel<<<128, B, 0, stream>>>(g, gmax);
  pool_exp_kernel<<<512, 128, 0, stream>>>(out, g, gmax, gacc, gsum);
  finalize_kernel<<<1, 128, 0, stream>>>(gacc, gsum, out);
}

// Round 14
// 475.686 us; speedup vs baseline: 1.0024x; 1.0024x over previous
//
#include <hip/hip_runtime.h>

#define NN 60000
#define NE 300000
typedef unsigned short ush;

static inline int cdiv(int a, int b) { return (a + b - 1) / b; }

__device__ inline unsigned ord_enc(float x) {
  unsigned u = __float_as_uint(x);
  return (u & 0x80000000u) ? ~u : (u | 0x80000000u);
}
__device__ inline float ord_dec(unsigned u) {
  return __uint_as_float((u & 0x80000000u) ? (u & 0x7fffffffu) : ~u);
}
__device__ inline float bf2f(unsigned u16) { return __uint_as_float(u16 << 16); }
__device__ inline ush f2bf(float x) {
  unsigned u = __float_as_uint(x);
  return (ush)((u + 0x7FFFu + ((u >> 16) & 1u)) >> 16);
}
__device__ inline unsigned pack2(float lo, float hi) {
  return ((unsigned)f2bf(hi) << 16) | (unsigned)f2bf(lo);
}
__device__ inline float dot8(float4 ea, float4 eb, uint4 zv) {
  float a = ea.x * bf2f(zv.x & 0xffff);
  a = fmaf(ea.y, bf2f(zv.x >> 16), a);
  a = fmaf(ea.z, bf2f(zv.y & 0xffff), a);
  a = fmaf(ea.w, bf2f(zv.y >> 16), a);
  a = fmaf(eb.x, bf2f(zv.z & 0xffff), a);
  a = fmaf(eb.y, bf2f(zv.z >> 16), a);
  a = fmaf(eb.z, bf2f(zv.w & 0xffff), a);
  a = fmaf(eb.w, bf2f(zv.w >> 16), a);
  return a;
}

// ================= CSR build (dst-sorted) =================
__global__ void deg_kernel(const int* __restrict__ key, int* __restrict__ deg) {
  int e = blockIdx.x * blockDim.x + threadIdx.x;
  if (e < NE) atomicAdd(deg + key[e], 1);
}

__global__ void scan1_kernel(const int* __restrict__ deg, int* __restrict__ rowptr,
                             int* __restrict__ partial) {
  __shared__ int s[256];
  int i = blockIdx.x * 256 + threadIdx.x;
  int v = (i < NN) ? deg[i] : 0;
  s[threadIdx.x] = v;
  __syncthreads();
  for (int off = 1; off < 256; off <<= 1) {
    int t = (threadIdx.x >= off) ? s[threadIdx.x - off] : 0;
    __syncthreads();
    s[threadIdx.x] += t;
    __syncthreads();
  }
  if (i < NN) rowptr[i] = s[threadIdx.x] - v;
  if (threadIdx.x == 255) partial[blockIdx.x] = s[255];
}

__global__ void scan2_kernel(int* __restrict__ partial, int nb) {
  __shared__ int s[256];
  int v = (threadIdx.x < nb) ? partial[threadIdx.x] : 0;
  s[threadIdx.x] = v;
  __syncthreads();
  for (int off = 1; off < 256; off <<= 1) {
    int t = (threadIdx.x >= off) ? s[threadIdx.x - off] : 0;
    __syncthreads();
    s[threadIdx.x] += t;
    __syncthreads();
  }
  if (threadIdx.x < nb) partial[threadIdx.x] = s[threadIdx.x] - v;
}

__global__ void scan3_kernel(int* __restrict__ rowptr, const int* __restrict__ partial,
                             int* __restrict__ cursor) {
  int i = blockIdx.x * 256 + threadIdx.x;
  if (i < NN) {
    int r = rowptr[i] + partial[blockIdx.x];
    rowptr[i] = r;
    cursor[i] = r;
  }
}

__global__ void scatter_dst_kernel(const int* __restrict__ src, const int* __restrict__ dst,
                                   int* __restrict__ cursor, int* __restrict__ src_s,
                                   int* __restrict__ dst_s, int* __restrict__ eid_s) {
  int e = blockIdx.x * blockDim.x + threadIdx.x;
  if (e >= NE) return;
  int d = dst[e];
  int j = atomicAdd(cursor + d, 1);
  src_s[j] = src[e];
  dst_s[j] = d;
  eid_s[j] = e;
}

// permute ef rows into dst-sorted order (sequential write, gathered read)
__global__ void permute_ef_kernel(const float* __restrict__ ef, const int* __restrict__ eid_s,
                                  float* __restrict__ ef_s) {
  int j = blockIdx.x * blockDim.x + threadIdx.x;
  if (j >= NE * 4) return;
  int slot = j >> 2, c = j & 3;
  int e = eid_s[slot];
  ((float4*)ef_s)[(size_t)slot * 4 + c] = ((const float4*)ef)[(size_t)e * 4 + c];
}

// ---------------- fold: precompute folded weight products (7424 dots of length 64) -------
__global__ void fold_kernel(const float* __restrict__ fp_w, const float* __restrict__ fp_b,
                            const float* __restrict__ ep_w, const float* __restrict__ ep_b,
                            const float* __restrict__ fij, const float* __restrict__ ebias,
                            const float* __restrict__ ni, const float* __restrict__ nj,
                            const float* __restrict__ node, float* __restrict__ fold) {
  int t = blockIdx.x * blockDim.x + threadIdx.x;
  if (t >= 7424) return;
  int o = t & 63;
  const float* A;
  const float* B;
  float init = 0.f;
  if (t < 1024)      { A = ep_w + (size_t)(t >> 6) * 64; B = fij + o; }
  else if (t < 1088) { A = ep_b; B = fij + o; init = ebias[o]; }
  else if (t < 3136) { A = fp_w + (size_t)((t - 1088) >> 6) * 64; B = ni + o; }
  else if (t < 5184) { A = fp_w + (size_t)((t - 3136) >> 6) * 64; B = nj + o; }
  else if (t < 7232) { A = fp_w + (size_t)((t - 5184) >> 6) * 64; B = node + o; }
  else if (t < 7296) { A = fp_b; B = ni + o; }
  else if (t < 7360) { A = fp_b; B = nj + o; }
  else               { A = fp_b; B = node + o; }
  float a = init;
  for (int i = 0; i < 64; ++i) a = fmaf(A[i], B[(size_t)i * 64], a);
  fold[t] = a;
}

// ---------------- transpose nn_w/nn_b into W2[32][576]: W2[i][o*16+k]=nn_w[k][i][o] ------
__global__ void nnwt_kernel(const float* __restrict__ nn_w, const float* __restrict__ nn_b,
                            float* __restrict__ W2) {
  int t = blockIdx.x * blockDim.x + threadIdx.x;
  if (t >= 32 * 576) return;
  int i = t / 576, c = t % 576;
  float v = 0.f;
  if (c < 512) v = nn_w[(size_t)(c & 15) * 1024 + i * 32 + (c >> 4)];
  else if (c < 544) v = nn_b[i * 32 + (c - 512)];
  W2[t] = v;
}

// ---------------- tiled GEMM (rows x K) @ (K x 64) -> bf16 out; 3 weight sets ------------
template <int K, bool BIAS>
__global__ __launch_bounds__(256, 2) void gemm3_kernel(
    const float* __restrict__ A, const float* __restrict__ W0, const float* __restrict__ W1,
    const float* __restrict__ W2, const float* __restrict__ b0, const float* __restrict__ b1,
    const float* __restrict__ b2, ush* __restrict__ o0, ush* __restrict__ o1,
    ush* __restrict__ o2, int rows) {
  __shared__ float sA[128][K + 1];
  __shared__ float sW[K][64];
  const float* W = blockIdx.y == 0 ? W0 : blockIdx.y == 1 ? W1 : W2;
  const float* bb = blockIdx.y == 0 ? b0 : blockIdx.y == 1 ? b1 : b2;
  ush* out = blockIdx.y == 0 ? o0 : blockIdx.y == 1 ? o1 : o2;
  int t = threadIdx.x;
  int r0 = blockIdx.x * 128;
  for (int i = t; i < K * 16; i += 256) ((float4*)sW)[i] = ((const float4*)W)[i];
  for (int i = t; i < 128 * (K / 4); i += 256) {
    int rr = i / (K / 4), cc = i % (K / 4);
    float4 v = (r0 + rr < rows) ? ((const float4*)(A + (size_t)(r0 + rr) * K))[cc]
                                : make_float4(0.f, 0.f, 0.f, 0.f);
    sA[rr][cc * 4 + 0] = v.x;
    sA[rr][cc * 4 + 1] = v.y;
    sA[rr][cc * 4 + 2] = v.z;
    sA[rr][cc * 4 + 3] = v.w;
  }
  __syncthreads();
  int rg = t >> 3, cg = t & 7;
  float acc[4][8];
#pragma unroll
  for (int i = 0; i < 4; ++i)
#pragma unroll
    for (int j = 0; j < 8; ++j) acc[i][j] = 0.f;
#pragma unroll 8
  for (int k = 0; k < K; ++k) {
    float a0 = sA[rg * 4 + 0][k], a1 = sA[rg * 4 + 1][k];
    float a2 = sA[rg * 4 + 2][k], a3 = sA[rg * 4 + 3][k];
    float4 wA = *(const float4*)&sW[k][cg * 8];
    float4 wB = *(const float4*)&sW[k][cg * 8 + 4];
#pragma unroll
    for (int i = 0; i < 4; ++i) {
      float a = i == 0 ? a0 : i == 1 ? a1 : i == 2 ? a2 : a3;
      acc[i][0] = fmaf(a, wA.x, acc[i][0]); acc[i][1] = fmaf(a, wA.y, acc[i][1]);
      acc[i][2] = fmaf(a, wA.z, acc[i][2]); acc[i][3] = fmaf(a, wA.w, acc[i][3]);
      acc[i][4] = fmaf(a, wB.x, acc[i][4]); acc[i][5] = fmaf(a, wB.y, acc[i][5]);
      acc[i][6] = fmaf(a, wB.z, acc[i][6]); acc[i][7] = fmaf(a, wB.w, acc[i][7]);
    }
  }
  float bv[8];
#pragma unroll
  for (int j = 0; j < 8; ++j) bv[j] = BIAS ? bb[cg * 8 + j] : 0.f;
#pragma unroll
  for (int i = 0; i < 4; ++i) {
    int r = r0 + rg * 4 + i;
    if (r < rows) {
      uint4 pv;
      pv.x = pack2(acc[i][0] + bv[0], acc[i][1] + bv[1]);
      pv.y = pack2(acc[i][2] + bv[2], acc[i][3] + bv[3]);
      pv.z = pack2(acc[i][4] + bv[4], acc[i][5] + bv[5]);
      pv.w = pack2(acc[i][6] + bv[6], acc[i][7] + bv[7]);
      *(uint4*)(out + (size_t)r * 64 + cg * 8) = pv;
    }
  }
}

// ---------------- zq as tiled GEMM: face(NNx32) @ W2(32x576) -> z bf16 | q f32 -----------
__global__ __launch_bounds__(256, 2) void gemm_zq_kernel(
    const float* __restrict__ A, const float* __restrict__ W2, ush* __restrict__ z,
    float* __restrict__ q, int rows) {
  __shared__ float sA[128][33];
  __shared__ float sW[32][64];
  int t = threadIdx.x;
  int r0 = blockIdx.x * 128;
  int c0 = blockIdx.y * 64;
  for (int i = t; i < 32 * 16; i += 256) {
    int ri = i / 16, cc = i % 16;
    float4 v = *(const float4*)(W2 + (size_t)ri * 576 + c0 + cc * 4);
    *(float4*)&sW[ri][cc * 4] = v;
  }
  for (int i = t; i < 128 * 8; i += 256) {
    int rr = i / 8, cc = i % 8;
    float4 v = (r0 + rr < rows) ? ((const float4*)(A + (size_t)(r0 + rr) * 32))[cc]
                                : make_float4(0.f, 0.f, 0.f, 0.f);
    sA[rr][cc * 4 + 0] = v.x;
    sA[rr][cc * 4 + 1] = v.y;
    sA[rr][cc * 4 + 2] = v.z;
    sA[rr][cc * 4 + 3] = v.w;
  }
  __syncthreads();
  int rg = t >> 3, cg = t & 7;
  float acc[4][8];
#pragma unroll
  for (int i = 0; i < 4; ++i)
#pragma unroll
    for (int j = 0; j < 8; ++j) acc[i][j] = 0.f;
#pragma unroll 8
  for (int k = 0; k < 32; ++k) {
    float a0 = sA[rg * 4 + 0][k], a1 = sA[rg * 4 + 1][k];
    float a2 = sA[rg * 4 + 2][k], a3 = sA[rg * 4 + 3][k];
    float4 wA = *(const float4*)&sW[k][cg * 8];
    float4 wB = *(const float4*)&sW[k][cg * 8 + 4];
#pragma unroll
    for (int i = 0; i < 4; ++i) {
      float a = i == 0 ? a0 : i == 1 ? a1 : i == 2 ? a2 : a3;
      acc[i][0] = fmaf(a, wA.x, acc[i][0]); acc[i][1] = fmaf(a, wA.y, acc[i][1]);
      acc[i][2] = fmaf(a, wA.z, acc[i][2]); acc[i][3] = fmaf(a, wA.w, acc[i][3]);
      acc[i][4] = fmaf(a, wB.x, acc[i][4]); acc[i][5] = fmaf(a, wB.y, acc[i][5]);
      acc[i][6] = fmaf(a, wB.z, acc[i][6]); acc[i][7] = fmaf(a, wB.w, acc[i][7]);
    }
  }
#pragma unroll
  for (int i = 0; i < 4; ++i) {
    int r = r0 + rg * 4 + i;
    if (r < rows) {
      if (blockIdx.y < 8) {
        int c = c0 + cg * 8;
        uint4 pv;
        pv.x = pack2(acc[i][0], acc[i][1]);
        pv.y = pack2(acc[i][2], acc[i][3]);
        pv.z = pack2(acc[i][4], acc[i][5]);
        pv.w = pack2(acc[i][6], acc[i][7]);
        *(uint4*)(z + (size_t)r * 512 + c) = pv;
      } else if (cg < 4) {
        float* qp = q + (size_t)r * 32 + cg * 8;
        *(float4*)qp = make_float4(acc[i][0], acc[i][1], acc[i][2], acc[i][3]);
        *(float4*)(qp + 4) = make_float4(acc[i][4], acc[i][5], acc[i][6], acc[i][7]);
      }
    }
  }
}

// ---------------- edge GEMM + fused f_out epilogue (edges in dst-sorted order) -----------
template <int K, bool STORE, bool ABF>
__global__ __launch_bounds__(256, 2) void gemm_fout_kernel(
    const void* __restrict__ Ap, const float* __restrict__ W, const float* __restrict__ bias,
    const ush* __restrict__ hs, const ush* __restrict__ hd, const int* __restrict__ src_s,
    const int* __restrict__ dst_s, const float* __restrict__ attn, ush* __restrict__ fstore,
    float* __restrict__ logit) {
  __shared__ float sA[128][K + 1];
  __shared__ float sW[K][64];
  int t = threadIdx.x;
  int r0 = blockIdx.x * 128;
  for (int i = t; i < K * 16; i += 256) ((float4*)sW)[i] = ((const float4*)W)[i];
  if (ABF) {
    const ush* A = (const ush*)Ap;
    for (int i = t; i < 128 * (K / 8); i += 256) {
      int rr = i / (K / 8), cc = i % (K / 8);
      uint4 v = (r0 + rr < NE) ? ((const uint4*)(A + (size_t)(r0 + rr) * K))[cc]
                               : make_uint4(0, 0, 0, 0);
      float* dp = &sA[rr][cc * 8];
      dp[0] = bf2f(v.x & 0xffff); dp[1] = bf2f(v.x >> 16);
      dp[2] = bf2f(v.y & 0xffff); dp[3] = bf2f(v.y >> 16);
      dp[4] = bf2f(v.z & 0xffff); dp[5] = bf2f(v.z >> 16);
      dp[6] = bf2f(v.w & 0xffff); dp[7] = bf2f(v.w >> 16);
    }
  } else {
    const float* A = (const float*)Ap;
    for (int i = t; i < 128 * (K / 4); i += 256) {
      int rr = i / (K / 4), cc = i % (K / 4);
      float4 v = (r0 + rr < NE) ? ((const float4*)(A + (size_t)(r0 + rr) * K))[cc]
                                : make_float4(0.f, 0.f, 0.f, 0.f);
      sA[rr][cc * 4 + 0] = v.x;
      sA[rr][cc * 4 + 1] = v.y;
      sA[rr][cc * 4 + 2] = v.z;
      sA[rr][cc * 4 + 3] = v.w;
    }
  }
  __syncthreads();
  int rg = t >> 3, cg = t & 7;
  float acc[4][8];
#pragma unroll
  for (int i = 0; i < 4; ++i)
#pragma unroll
    for (int j = 0; j < 8; ++j) acc[i][j] = 0.f;
#pragma unroll 8
  for (int k = 0; k < K; ++k) {
    float a0 = sA[rg * 4 + 0][k], a1 = sA[rg * 4 + 1][k];
    float a2 = sA[rg * 4 + 2][k], a3 = sA[rg * 4 + 3][k];
    float4 wA = *(const float4*)&sW[k][cg * 8];
    float4 wB = *(const float4*)&sW[k][cg * 8 + 4];
#pragma unroll
    for (int i = 0; i < 4; ++i) {
      float a = i == 0 ? a0 : i == 1 ? a1 : i == 2 ? a2 : a3;
      acc[i][0] = fmaf(a, wA.x, acc[i][0]); acc[i][1] = fmaf(a, wA.y, acc[i][1]);
      acc[i][2] = fmaf(a, wA.z, acc[i][2]); acc[i][3] = fmaf(a, wA.w, acc[i][3]);
      acc[i][4] = fmaf(a, wB.x, acc[i][4]); acc[i][5] = fmaf(a, wB.y, acc[i][5]);
      acc[i][6] = fmaf(a, wB.z, acc[i][6]); acc[i][7] = fmaf(a, wB.w, acc[i][7]);
    }
  }
  float bv[8], av[8];
#pragma unroll
  for (int j = 0; j < 8; ++j) {
    bv[j] = bias[cg * 8 + j];
    av[j] = attn[cg * 8 + j];
  }
#pragma unroll
  for (int i = 0; i < 4; ++i) {
    int r = r0 + rg * 4 + i;
    if (r < NE) {
      int s = src_s[r], d = dst_s[r];
      uint4 hv = *(const uint4*)(hs + (size_t)s * 64 + cg * 8);
      uint4 dv = *(const uint4*)(hd + (size_t)d * 64 + cg * 8);
      float fo[8];
      fo[0] = acc[i][0] + bf2f(hv.x & 0xffff) + bf2f(dv.x & 0xffff) + bv[0];
      fo[1] = acc[i][1] + bf2f(hv.x >> 16)    + bf2f(dv.x >> 16)    + bv[1];
      fo[2] = acc[i][2] + bf2f(hv.y & 0xffff) + bf2f(dv.y & 0xffff) + bv[2];
      fo[3] = acc[i][3] + bf2f(hv.y >> 16)    + bf2f(dv.y >> 16)    + bv[3];
      fo[4] = acc[i][4] + bf2f(hv.z & 0xffff) + bf2f(dv.z & 0xffff) + bv[4];
      fo[5] = acc[i][5] + bf2f(hv.z >> 16)    + bf2f(dv.z >> 16)    + bv[5];
      fo[6] = acc[i][6] + bf2f(hv.w & 0xffff) + bf2f(dv.w & 0xffff) + bv[6];
      fo[7] = acc[i][7] + bf2f(hv.w >> 16)    + bf2f(dv.w >> 16)    + bv[7];
      float p = 0.f;
#pragma unroll
      for (int j = 0; j < 8; ++j) {
        fo[j] = fo[j] >= 0.f ? fo[j] : 0.01f * fo[j];  // LeakyReLU
        p = fmaf(fo[j], av[j], p);
      }
      if (STORE) {
        uint4 pv;
        pv.x = pack2(fo[0], fo[1]);
        pv.y = pack2(fo[2], fo[3]);
        pv.z = pack2(fo[4], fo[5]);
        pv.w = pack2(fo[6], fo[7]);
        *(uint4*)(fstore + (size_t)r * 64 + cg * 8) = pv;
      }
      p += __shfl_xor(p, 1, 64);
      p += __shfl_xor(p, 2, 64);
      p += __shfl_xor(p, 4, 64);
      if (cg == 0) logit[r] = p;
    }
  }
}

// ---------------- EGAT: gather-aggregate, no max pre-pass (logits ~O(1), exp f32-safe) ---
__global__ __launch_bounds__(256, 8) void agg_gather_kernel(
    const ush* __restrict__ hn, const float* __restrict__ logit, const int* __restrict__ rowptr,
    const int* __restrict__ deg, const int* __restrict__ src_s, float* __restrict__ hnew) {
  int wave = (blockIdx.x * blockDim.x + threadIdx.x) >> 6;
  int lane = threadIdx.x & 63;
  if (wave >= NN) return;
  int n = wave, d = deg[n], r0 = rowptr[n];
  if (d == 0) {
    hnew[(size_t)n * 64 + lane] = 0.f;
    return;
  }
  float sum = 0.f, acc0 = 0.f, acc1 = 0.f, acc2 = 0.f, acc3 = 0.f;
  int j = 0;
  for (; j + 3 < d; j += 4) {
    int jj = r0 + j;
    int s0 = src_s[jj + 0], s1 = src_s[jj + 1], s2 = src_s[jj + 2], s3 = src_s[jj + 3];
    float l0 = logit[jj + 0], l1 = logit[jj + 1], l2 = logit[jj + 2], l3 = logit[jj + 3];
    ush h0 = hn[(size_t)s0 * 64 + lane];
    ush h1 = hn[(size_t)s1 * 64 + lane];
    ush h2 = hn[(size_t)s2 * 64 + lane];
    ush h3 = hn[(size_t)s3 * 64 + lane];
    float w0 = __expf(l0), w1 = __expf(l1);
    float w2 = __expf(l2), w3 = __expf(l3);
    sum += (w0 + w1) + (w2 + w3);
    acc0 = fmaf(w0, bf2f(h0), acc0);
    acc1 = fmaf(w1, bf2f(h1), acc1);
    acc2 = fmaf(w2, bf2f(h2), acc2);
    acc3 = fmaf(w3, bf2f(h3), acc3);
  }
  for (; j < d; ++j) {
    int jj = r0 + j;
    float w = __expf(logit[jj]);
    sum += w;
    acc0 = fmaf(w, bf2f(hn[(size_t)src_s[jj] * 64 + lane]), acc0);
  }
  hnew[(size_t)n * 64 + lane] = ((acc0 + acc1) + (acc2 + acc3)) / sum;
}

// ---------------- NNConv stage 2 (gather, 4-deep load-then-FMA pipeline) -----------------
__global__ __launch_bounds__(256, 8) void nnconv_gather_kernel(
    const ush* __restrict__ z, const float* __restrict__ q, const float* __restrict__ ef_s,
    const int* __restrict__ rowptr, const int* __restrict__ deg, const int* __restrict__ src_s,
    float* __restrict__ sArr) {
  int wave = (blockIdx.x * blockDim.x + threadIdx.x) >> 6;
  int lane = threadIdx.x & 63;
  if (wave >= NN) return;
  int n = wave, d = deg[n], r0 = rowptr[n];
  int o = lane >> 1, half = lane & 1;
  float acc0 = 0.f, acc1 = 0.f, acc2 = 0.f, acc3 = 0.f;
  int j = 0;
  for (; j + 3 < d; j += 4) {
    int jj = r0 + j;
    int s0 = src_s[jj + 0], s1 = src_s[jj + 1], s2 = src_s[jj + 2], s3 = src_s[jj + 3];
    uint4 zv0 = *(const uint4*)(z + (size_t)s0 * 512 + lane * 8);
    uint4 zv1 = *(const uint4*)(z + (size_t)s1 * 512 + lane * 8);
    uint4 zv2 = *(const uint4*)(z + (size_t)s2 * 512 + lane * 8);
    uint4 zv3 = *(const uint4*)(z + (size_t)s3 * 512 + lane * 8);
    const float4* ep0 = (const float4*)(ef_s + (size_t)(jj + 0) * 16 + half * 8);
    const float4* ep1 = (const float4*)(ef_s + (size_t)(jj + 1) * 16 + half * 8);
    const float4* ep2 = (const float4*)(ef_s + (size_t)(jj + 2) * 16 + half * 8);
    const float4* ep3 = (const float4*)(ef_s + (size_t)(jj + 3) * 16 + half * 8);
    float4 ea0 = ep0[0], eb0 = ep0[1];
    float4 ea1 = ep1[0], eb1 = ep1[1];
    float4 ea2 = ep2[0], eb2 = ep2[1];
    float4 ea3 = ep3[0], eb3 = ep3[1];
    float q0 = 0.f, q1 = 0.f, q2 = 0.f, q3 = 0.f;
    if (half == 0) {
      q0 = q[(size_t)s0 * 32 + o];
      q1 = q[(size_t)s1 * 32 + o];
      q2 = q[(size_t)s2 * 32 + o];
      q3 = q[(size_t)s3 * 32 + o];
    }
    acc0 += dot8(ea0, eb0, zv0) + q0;
    acc1 += dot8(ea1, eb1, zv1) + q1;
    acc2 += dot8(ea2, eb2, zv2) + q2;
    acc3 += dot8(ea3, eb3, zv3) + q3;
  }
  for (; j < d; ++j) {
    int jj = r0 + j;
    int s = src_s[jj];
    const float4* ep = (const float4*)(ef_s + (size_t)jj * 16 + half * 8);
    float4 ea = ep[0], eb = ep[1];
    uint4 zv = *(const uint4*)(z + (size_t)s * 512 + lane * 8);
    float qv = (half == 0) ? q[(size_t)s * 32 + o] : 0.f;
    acc0 += dot8(ea, eb, zv) + qv;
  }
  float acc = (acc0 + acc1) + (acc2 + acc3);
  acc += __shfl_xor(acc, 1, 64);
  if (half == 0) sArr[(size_t)n * 32 + o] = acc;
}

// ---------------- combine node_features + gate logit (fused; wave per node) --------------
__global__ void combine_gate_kernel(const float* __restrict__ hfin, const float* __restrict__ sArr,
                                    const int* __restrict__ deg, const float* __restrict__ nn_bias,
                                    const float* __restrict__ gate_w, const float* __restrict__ gate_b,
                                    float* __restrict__ out, float* __restrict__ g) {
  int wave = (blockIdx.x * blockDim.x + threadIdx.x) >> 6;
  int lane = threadIdx.x & 63;
  if (wave >= NN) return;
  int n = wave;
  float v0 = hfin[(size_t)n * 64 + lane];
  int c1 = lane + 64;
  float v1 = (c1 < 96)
                 ? sArr[(size_t)n * 32 + (c1 - 64)] / fmaxf((float)deg[n], 1.0f) + nn_bias[c1 - 64]
                 : 0.f;
  out[(size_t)n * 128 + lane] = v0;
  out[(size_t)n * 128 + c1] = v1;
  float p = v0 * gate_w[lane] + ((c1 < 96) ? v1 * gate_w[c1] : 0.f);
#pragma unroll
  for (int off = 32; off; off >>= 1) p += __shfl_xor(p, off, 64);
  if (lane == 0) g[n] = p + gate_b[0];
}

// ---------------- max over g (block-reduced, 1 atomic per block) ----------------
__global__ void gate_max_kernel(const float* __restrict__ g, unsigned* __restrict__ gmax) {
  int tid = blockIdx.x * blockDim.x + threadIdx.x;
  int stride = gridDim.x * blockDim.x;
  float v = -3.0e38f;
  for (int n = tid; n < NN; n += stride) v = fmaxf(v, g[n]);
#pragma unroll
  for (int off = 32; off; off >>= 1) v = fmaxf(v, __shfl_xor(v, off, 64));
  __shared__ float sm[4];
  int lane = threadIdx.x & 63, wid = threadIdx.x >> 6;
  if (lane == 0) sm[wid] = v;
  __syncthreads();
  if (threadIdx.x == 0) {
    float m = fmaxf(fmaxf(sm[0], sm[1]), fmaxf(sm[2], sm[3]));
    atomicMax(gmax, ord_enc(m));
  }
}

// ---------------- pooling: exp + weighted accumulate (fused) ----------------
__global__ void pool_exp_kernel(const float* __restrict__ nf, const float* __restrict__ g,
                                const unsigned* __restrict__ gmax, float* __restrict__ gacc,
                                float* __restrict__ gsum) {
  int o = threadIdx.x;  // blockDim = 128
  float m = ord_dec(*gmax);
  float acc = 0.f, ws = 0.f;
  for (int n = blockIdx.x; n < NN; n += gridDim.x) {
    float w = __expf(g[n] - m);
    ws += w;
    acc += w * nf[(size_t)n * 128 + o];
  }
  atomicAdd(gacc + o, acc);
  if (o == 0) atomicAdd(gsum, ws);
}

__global__ void finalize_kernel(const float* __restrict__ gacc, const float* __restrict__ gsum,
                                float* __restrict__ out) {
  int o = threadIdx.x;
  if (o < 128) out[(size_t)NN * 128 + o] = gacc[o] / gsum[0];
}

extern "C" void kernel_launch(void* const* d_in, const int* in_sizes, int n_in,
                              void* d_out, int out_size, void* d_ws, size_t ws_size,
                              hipStream_t stream) {
  const float* face    = (const float*)d_in[0];
  const float* ef      = (const float*)d_in[1];
  const float* fp_w    = (const float*)d_in[2];
  const float* fp_b    = (const float*)d_in[3];
  const float* ep_w    = (const float*)d_in[4];
  const float* ep_b    = (const float*)d_in[5];
  const float* nn_w    = (const float*)d_in[6];
  const float* nn_b    = (const float*)d_in[7];
  const float* nn_bias = (const float*)d_in[8];
  const float* gate_w  = (const float*)d_in[9];
  const float* gate_b  = (const float*)d_in[10];
  const int*   src     = (const int*)d_in[11];
  const int*   dst     = (const int*)d_in[12];
  const float* e1_attn = (const float*)d_in[17];
  const float* e2_ni   = (const float*)d_in[19];
  const float* e2_nj   = (const float*)d_in[20];
  const float* e2_fij  = (const float*)d_in[21];
  const float* e2_node = (const float*)d_in[22];
  const float* e2_attn = (const float*)d_in[23];
  const float* e2_bias = (const float*)d_in[24];
  float* out = (float*)d_out;

  char* p = (char*)d_ws;
  auto alloc = [&](size_t nfloats) {
    float* r = (float*)p;
    p += ((nfloats * 4 + 255) / 256) * 256;
    return r;
  };
  float* h0 = alloc((size_t)NN * 64);   // layer-2 output
  float* h1 = alloc((size_t)NN * 64);   // layer-1 output; q aliases after EGAT
  char* regionC = p;                    // hs16|hd16|hn16|f116 = 61.4 MB, dead after EGAT
  ush* hs16 = (ush*)alloc((size_t)NN * 32);   // NN*64 bf16
  ush* hd16 = (ush*)alloc((size_t)NN * 32);
  ush* hn16 = (ush*)alloc((size_t)NN * 32);
  ush* f116 = (ush*)alloc((size_t)NE * 32);   // NE*64 bf16 (dst-sorted order)
  float* logit = alloc(NE);                   // dst-sorted order
  float* sArr  = alloc((size_t)NN * 32);
  float* g     = alloc(NN);
  float* gacc  = alloc(128);
  float* gsum  = alloc(1);
  unsigned* gmax = (unsigned*)alloc(1);
  float* fold  = alloc(7424);
  float* W2    = alloc(32 * 576);
  // dst-CSR
  int* deg    = (int*)alloc(NN);
  int* rowptr = (int*)alloc(NN);
  int* cursor = (int*)alloc(NN);
  int* partial = (int*)alloc(256);
  int* src_s  = (int*)alloc(NE);
  int* dst_s  = (int*)alloc(NE);
  int* eid_s  = (int*)alloc(NE);
  float* ef_s = alloc((size_t)NE * 16);       // permuted edge features
  ush* z16 = (ush*)regionC;             // NN*512 bf16 = 61.44 MB == regionC exactly
  float* q = h1;                        // NN*32 <= h1's NN*64, h1 dead post-EGAT

  const float* Wf1  = fold;
  const float* b1f  = fold + 1024;
  const float* Wni1 = fold + 1088;
  const float* Wnj1 = fold + 3136;
  const float* Wno1 = fold + 5184;
  const float* bni1 = fold + 7232;
  const float* bnj1 = fold + 7296;
  const float* bno1 = fold + 7360;

  const int B = 256;
  const int NGB = cdiv(NN, 128);
  const int EGB = cdiv(NE, 128);
  const int NB256 = cdiv(NN, 256);

  // ---- CSR build (dst-sorted) + edge permutation ----
  hipMemsetAsync(deg, 0, NN * 4, stream);
  deg_kernel<<<cdiv(NE, B), B, 0, stream>>>(dst, deg);
  scan1_kernel<<<NB256, 256, 0, stream>>>(deg, rowptr, partial);
  scan2_kernel<<<1, 256, 0, stream>>>(partial, NB256);
  scan3_kernel<<<NB256, 256, 0, stream>>>(rowptr, partial, cursor);
  scatter_dst_kernel<<<cdiv(NE, B), B, 0, stream>>>(src, dst, cursor, src_s, dst_s, eid_s);
  permute_ef_kernel<<<cdiv(NE * 4, B), B, 0, stream>>>(ef, eid_s, ef_s);

  // folded weights + nn_w transpose (tiny)
  fold_kernel<<<29, B, 0, stream>>>(fp_w, fp_b, ep_w, ep_b,
                                    (const float*)d_in[15], (const float*)d_in[18],
                                    (const float*)d_in[13], (const float*)d_in[14],
                                    (const float*)d_in[16], fold);
  nnwt_kernel<<<72, B, 0, stream>>>(nn_w, nn_b, W2);

  // ---- EGAT layer 1 (edges processed in dst-sorted order) ----
  gemm3_kernel<32, true><<<dim3(NGB, 3), B, 0, stream>>>(face, Wni1, Wnj1, Wno1, bni1, bnj1,
                                                         bno1, hs16, hd16, hn16, NN);
  gemm_fout_kernel<16, true, false><<<EGB, B, 0, stream>>>(ef_s, Wf1, b1f, hs16, hd16, src_s,
                                                           dst_s, e1_attn, f116, logit);
  agg_gather_kernel<<<cdiv(NN * 64, B), B, 0, stream>>>(hn16, logit, rowptr, deg, src_s, h1);

  // ---- EGAT layer 2 ----
  gemm3_kernel<64, false><<<dim3(NGB, 3), B, 0, stream>>>(h1, e2_ni, e2_nj, e2_node, nullptr,
                                                          nullptr, nullptr, hs16, hd16, hn16, NN);
  gemm_fout_kernel<64, false, true><<<EGB, B, 0, stream>>>(f116, e2_fij, e2_bias, hs16, hd16,
                                                           src_s, dst_s, e2_attn, nullptr, logit);
  agg_gather_kernel<<<cdiv(NN * 64, B), B, 0, stream>>>(hn16, logit, rowptr, deg, src_s, h0);

  // ---- NNConv (z16/q alias dead EGAT buffers — must run after EGAT) ----
  gemm_zq_kernel<<<dim3(NGB, 9), B, 0, stream>>>(face, W2, z16, q, NN);
  nnconv_gather_kernel<<<cdiv(NN * 64, B), B, 0, stream>>>(z16, q, ef_s, rowptr, deg, src_s,
                                                           sArr);

  // ---- combine node features + gate logits ----
  hipMemsetAsync(gacc, 0, 128 * 4, stream);
  hipMemsetAsync(gsum, 0, 4, stream);
  hipMemsetAsync(gmax, 0, 4, stream);
  combine_gate_kernel<<<cdiv(NN * 64, B), B, 0, stream>>>(h0, sArr, deg, nn_bias, gate_w,
                                                          gate_b, out, g);
  gate_max_kernel<<<128, B, 0, stream>>>(g, gmax);
  pool_exp_kernel<<<512, 128, 0, stream>>>(out, g, gmax, gacc, gsum);
  finalize_kernel<<<1, 128, 0, stream>>>(gacc, gsum, out);
}

// Round 15
// 395.123 us; speedup vs baseline: 1.2067x; 1.2039x over previous
//
#include <hip/hip_runtime.h>

#define NN 60000
#define NE 300000
typedef unsigned short ush;

static inline int cdiv(int a, int b) { return (a + b - 1) / b; }

__device__ inline unsigned ord_enc(float x) {
  unsigned u = __float_as_uint(x);
  return (u & 0x80000000u) ? ~u : (u | 0x80000000u);
}
__device__ inline float ord_dec(unsigned u) {
  return __uint_as_float((u & 0x80000000u) ? (u & 0x7fffffffu) : ~u);
}
__device__ inline float bf2f(unsigned u16) { return __uint_as_float(u16 << 16); }
__device__ inline ush f2bf(float x) {
  unsigned u = __float_as_uint(x);
  return (ush)((u + 0x7FFFu + ((u >> 16) & 1u)) >> 16);
}
__device__ inline unsigned pack2(float lo, float hi) {
  return ((unsigned)f2bf(hi) << 16) | (unsigned)f2bf(lo);
}
__device__ inline float dot8(float4 ea, float4 eb, uint4 zv) {
  float a = ea.x * bf2f(zv.x & 0xffff);
  a = fmaf(ea.y, bf2f(zv.x >> 16), a);
  a = fmaf(ea.z, bf2f(zv.y & 0xffff), a);
  a = fmaf(ea.w, bf2f(zv.y >> 16), a);
  a = fmaf(eb.x, bf2f(zv.z & 0xffff), a);
  a = fmaf(eb.y, bf2f(zv.z >> 16), a);
  a = fmaf(eb.z, bf2f(zv.w & 0xffff), a);
  a = fmaf(eb.w, bf2f(zv.w >> 16), a);
  return a;
}

// ================= CSR build (dst-sorted) =================
__global__ void deg_kernel(const int* __restrict__ key, int* __restrict__ deg) {
  int e = blockIdx.x * blockDim.x + threadIdx.x;
  if (e < NE) atomicAdd(deg + key[e], 1);
}

__global__ void scan1_kernel(const int* __restrict__ deg, int* __restrict__ rowptr,
                             int* __restrict__ partial) {
  __shared__ int s[256];
  int i = blockIdx.x * 256 + threadIdx.x;
  int v = (i < NN) ? deg[i] : 0;
  s[threadIdx.x] = v;
  __syncthreads();
  for (int off = 1; off < 256; off <<= 1) {
    int t = (threadIdx.x >= off) ? s[threadIdx.x - off] : 0;
    __syncthreads();
    s[threadIdx.x] += t;
    __syncthreads();
  }
  if (i < NN) rowptr[i] = s[threadIdx.x] - v;
  if (threadIdx.x == 255) partial[blockIdx.x] = s[255];
}

__global__ void scan2_kernel(int* __restrict__ partial, int nb) {
  __shared__ int s[256];
  int v = (threadIdx.x < nb) ? partial[threadIdx.x] : 0;
  s[threadIdx.x] = v;
  __syncthreads();
  for (int off = 1; off < 256; off <<= 1) {
    int t = (threadIdx.x >= off) ? s[threadIdx.x - off] : 0;
    __syncthreads();
    s[threadIdx.x] += t;
    __syncthreads();
  }
  if (threadIdx.x < nb) partial[threadIdx.x] = s[threadIdx.x] - v;
}

__global__ void scan3_kernel(int* __restrict__ rowptr, const int* __restrict__ partial,
                             int* __restrict__ cursor) {
  int i = blockIdx.x * 256 + threadIdx.x;
  if (i < NN) {
    int r = rowptr[i] + partial[blockIdx.x];
    rowptr[i] = r;
    cursor[i] = r;
  }
}

__global__ void scatter_dst_kernel(const int* __restrict__ src, const int* __restrict__ dst,
                                   int* __restrict__ cursor, int* __restrict__ src_s,
                                   int* __restrict__ dst_s, int* __restrict__ eid_s) {
  int e = blockIdx.x * blockDim.x + threadIdx.x;
  if (e >= NE) return;
  int d = dst[e];
  int j = atomicAdd(cursor + d, 1);
  src_s[j] = src[e];
  dst_s[j] = d;
  eid_s[j] = e;
}

// permute ef rows into dst-sorted order (sequential write, gathered read)
__global__ void permute_ef_kernel(const float* __restrict__ ef, const int* __restrict__ eid_s,
                                  float* __restrict__ ef_s) {
  int j = blockIdx.x * blockDim.x + threadIdx.x;
  if (j >= NE * 4) return;
  int slot = j >> 2, c = j & 3;
  int e = eid_s[slot];
  ((float4*)ef_s)[(size_t)slot * 4 + c] = ((const float4*)ef)[(size_t)e * 4 + c];
}

// ---------------- fold: precompute folded weight products (7424 dots of length 64) -------
__global__ void fold_kernel(const float* __restrict__ fp_w, const float* __restrict__ fp_b,
                            const float* __restrict__ ep_w, const float* __restrict__ ep_b,
                            const float* __restrict__ fij, const float* __restrict__ ebias,
                            const float* __restrict__ ni, const float* __restrict__ nj,
                            const float* __restrict__ node, float* __restrict__ fold) {
  int t = blockIdx.x * blockDim.x + threadIdx.x;
  if (t >= 7424) return;
  int o = t & 63;
  const float* A;
  const float* B;
  float init = 0.f;
  if (t < 1024)      { A = ep_w + (size_t)(t >> 6) * 64; B = fij + o; }
  else if (t < 1088) { A = ep_b; B = fij + o; init = ebias[o]; }
  else if (t < 3136) { A = fp_w + (size_t)((t - 1088) >> 6) * 64; B = ni + o; }
  else if (t < 5184) { A = fp_w + (size_t)((t - 3136) >> 6) * 64; B = nj + o; }
  else if (t < 7232) { A = fp_w + (size_t)((t - 5184) >> 6) * 64; B = node + o; }
  else if (t < 7296) { A = fp_b; B = ni + o; }
  else if (t < 7360) { A = fp_b; B = nj + o; }
  else               { A = fp_b; B = node + o; }
  float a = init;
  for (int i = 0; i < 64; ++i) a = fmaf(A[i], B[(size_t)i * 64], a);
  fold[t] = a;
}

// ---------------- transpose nn_w/nn_b into W2[32][576]: W2[i][o*16+k]=nn_w[k][i][o] ------
__global__ void nnwt_kernel(const float* __restrict__ nn_w, const float* __restrict__ nn_b,
                            float* __restrict__ W2) {
  int t = blockIdx.x * blockDim.x + threadIdx.x;
  if (t >= 32 * 576) return;
  int i = t / 576, c = t % 576;
  float v = 0.f;
  if (c < 512) v = nn_w[(size_t)(c & 15) * 1024 + i * 32 + (c >> 4)];
  else if (c < 544) v = nn_b[i * 32 + (c - 512)];
  W2[t] = v;
}

// ---------------- tiled GEMM (rows x K) @ (K x 64) -> bf16 out; 3 weight sets ------------
template <int K, bool BIAS>
__global__ __launch_bounds__(256, 2) void gemm3_kernel(
    const float* __restrict__ A, const float* __restrict__ W0, const float* __restrict__ W1,
    const float* __restrict__ W2, const float* __restrict__ b0, const float* __restrict__ b1,
    const float* __restrict__ b2, ush* __restrict__ o0, ush* __restrict__ o1,
    ush* __restrict__ o2, int rows) {
  __shared__ float sA[128][K + 1];
  __shared__ float sW[K][64];
  const float* W = blockIdx.y == 0 ? W0 : blockIdx.y == 1 ? W1 : W2;
  const float* bb = blockIdx.y == 0 ? b0 : blockIdx.y == 1 ? b1 : b2;
  ush* out = blockIdx.y == 0 ? o0 : blockIdx.y == 1 ? o1 : o2;
  int t = threadIdx.x;
  int r0 = blockIdx.x * 128;
  for (int i = t; i < K * 16; i += 256) ((float4*)sW)[i] = ((const float4*)W)[i];
  for (int i = t; i < 128 * (K / 4); i += 256) {
    int rr = i / (K / 4), cc = i % (K / 4);
    float4 v = (r0 + rr < rows) ? ((const float4*)(A + (size_t)(r0 + rr) * K))[cc]
                                : make_float4(0.f, 0.f, 0.f, 0.f);
    sA[rr][cc * 4 + 0] = v.x;
    sA[rr][cc * 4 + 1] = v.y;
    sA[rr][cc * 4 + 2] = v.z;
    sA[rr][cc * 4 + 3] = v.w;
  }
  __syncthreads();
  int rg = t >> 3, cg = t & 7;
  float acc[4][8];
#pragma unroll
  for (int i = 0; i < 4; ++i)
#pragma unroll
    for (int j = 0; j < 8; ++j) acc[i][j] = 0.f;
#pragma unroll 8
  for (int k = 0; k < K; ++k) {
    float a0 = sA[rg * 4 + 0][k], a1 = sA[rg * 4 + 1][k];
    float a2 = sA[rg * 4 + 2][k], a3 = sA[rg * 4 + 3][k];
    float4 wA = *(const float4*)&sW[k][cg * 8];
    float4 wB = *(const float4*)&sW[k][cg * 8 + 4];
#pragma unroll
    for (int i = 0; i < 4; ++i) {
      float a = i == 0 ? a0 : i == 1 ? a1 : i == 2 ? a2 : a3;
      acc[i][0] = fmaf(a, wA.x, acc[i][0]); acc[i][1] = fmaf(a, wA.y, acc[i][1]);
      acc[i][2] = fmaf(a, wA.z, acc[i][2]); acc[i][3] = fmaf(a, wA.w, acc[i][3]);
      acc[i][4] = fmaf(a, wB.x, acc[i][4]); acc[i][5] = fmaf(a, wB.y, acc[i][5]);
      acc[i][6] = fmaf(a, wB.z, acc[i][6]); acc[i][7] = fmaf(a, wB.w, acc[i][7]);
    }
  }
  float bv[8];
#pragma unroll
  for (int j = 0; j < 8; ++j) bv[j] = BIAS ? bb[cg * 8 + j] : 0.f;
#pragma unroll
  for (int i = 0; i < 4; ++i) {
    int r = r0 + rg * 4 + i;
    if (r < rows) {
      uint4 pv;
      pv.x = pack2(acc[i][0] + bv[0], acc[i][1] + bv[1]);
      pv.y = pack2(acc[i][2] + bv[2], acc[i][3] + bv[3]);
      pv.z = pack2(acc[i][4] + bv[4], acc[i][5] + bv[5]);
      pv.w = pack2(acc[i][6] + bv[6], acc[i][7] + bv[7]);
      *(uint4*)(out + (size_t)r * 64 + cg * 8) = pv;
    }
  }
}

// ---------------- zq as tiled GEMM: face(NNx32) @ W2(32x576) -> z bf16 | q f32 -----------
__global__ __launch_bounds__(256, 2) void gemm_zq_kernel(
    const float* __restrict__ A, const float* __restrict__ W2, ush* __restrict__ z,
    float* __restrict__ q, int rows) {
  __shared__ float sA[128][33];
  __shared__ float sW[32][64];
  int t = threadIdx.x;
  int r0 = blockIdx.x * 128;
  int c0 = blockIdx.y * 64;
  for (int i = t; i < 32 * 16; i += 256) {
    int ri = i / 16, cc = i % 16;
    float4 v = *(const float4*)(W2 + (size_t)ri * 576 + c0 + cc * 4);
    *(float4*)&sW[ri][cc * 4] = v;
  }
  for (int i = t; i < 128 * 8; i += 256) {
    int rr = i / 8, cc = i % 8;
    float4 v = (r0 + rr < rows) ? ((const float4*)(A + (size_t)(r0 + rr) * 32))[cc]
                                : make_float4(0.f, 0.f, 0.f, 0.f);
    sA[rr][cc * 4 + 0] = v.x;
    sA[rr][cc * 4 + 1] = v.y;
    sA[rr][cc * 4 + 2] = v.z;
    sA[rr][cc * 4 + 3] = v.w;
  }
  __syncthreads();
  int rg = t >> 3, cg = t & 7;
  float acc[4][8];
#pragma unroll
  for (int i = 0; i < 4; ++i)
#pragma unroll
    for (int j = 0; j < 8; ++j) acc[i][j] = 0.f;
#pragma unroll 8
  for (int k = 0; k < 32; ++k) {
    float a0 = sA[rg * 4 + 0][k], a1 = sA[rg * 4 + 1][k];
    float a2 = sA[rg * 4 + 2][k], a3 = sA[rg * 4 + 3][k];
    float4 wA = *(const float4*)&sW[k][cg * 8];
    float4 wB = *(const float4*)&sW[k][cg * 8 + 4];
#pragma unroll
    for (int i = 0; i < 4; ++i) {
      float a = i == 0 ? a0 : i == 1 ? a1 : i == 2 ? a2 : a3;
      acc[i][0] = fmaf(a, wA.x, acc[i][0]); acc[i][1] = fmaf(a, wA.y, acc[i][1]);
      acc[i][2] = fmaf(a, wA.z, acc[i][2]); acc[i][3] = fmaf(a, wA.w, acc[i][3]);
      acc[i][4] = fmaf(a, wB.x, acc[i][4]); acc[i][5] = fmaf(a, wB.y, acc[i][5]);
      acc[i][6] = fmaf(a, wB.z, acc[i][6]); acc[i][7] = fmaf(a, wB.w, acc[i][7]);
    }
  }
#pragma unroll
  for (int i = 0; i < 4; ++i) {
    int r = r0 + rg * 4 + i;
    if (r < rows) {
      if (blockIdx.y < 8) {
        int c = c0 + cg * 8;
        uint4 pv;
        pv.x = pack2(acc[i][0], acc[i][1]);
        pv.y = pack2(acc[i][2], acc[i][3]);
        pv.z = pack2(acc[i][4], acc[i][5]);
        pv.w = pack2(acc[i][6], acc[i][7]);
        *(uint4*)(z + (size_t)r * 512 + c) = pv;
      } else if (cg < 4) {
        float* qp = q + (size_t)r * 32 + cg * 8;
        *(float4*)qp = make_float4(acc[i][0], acc[i][1], acc[i][2], acc[i][3]);
        *(float4*)(qp + 4) = make_float4(acc[i][4], acc[i][5], acc[i][6], acc[i][7]);
      }
    }
  }
}

// ---------------- edge GEMM + fused f_out epilogue (edges in dst-sorted order) -----------
template <int K, bool STORE, bool ABF>
__global__ __launch_bounds__(256, 2) void gemm_fout_kernel(
    const void* __restrict__ Ap, const float* __restrict__ W, const float* __restrict__ bias,
    const ush* __restrict__ hs, const ush* __restrict__ hd, const int* __restrict__ src_s,
    const int* __restrict__ dst_s, const float* __restrict__ attn, ush* __restrict__ fstore,
    float* __restrict__ logit) {
  __shared__ float sA[128][K + 1];
  __shared__ float sW[K][64];
  int t = threadIdx.x;
  int r0 = blockIdx.x * 128;
  for (int i = t; i < K * 16; i += 256) ((float4*)sW)[i] = ((const float4*)W)[i];
  if (ABF) {
    const ush* A = (const ush*)Ap;
    for (int i = t; i < 128 * (K / 8); i += 256) {
      int rr = i / (K / 8), cc = i % (K / 8);
      uint4 v = (r0 + rr < NE) ? ((const uint4*)(A + (size_t)(r0 + rr) * K))[cc]
                               : make_uint4(0, 0, 0, 0);
      float* dp = &sA[rr][cc * 8];
      dp[0] = bf2f(v.x & 0xffff); dp[1] = bf2f(v.x >> 16);
      dp[2] = bf2f(v.y & 0xffff); dp[3] = bf2f(v.y >> 16);
      dp[4] = bf2f(v.z & 0xffff); dp[5] = bf2f(v.z >> 16);
      dp[6] = bf2f(v.w & 0xffff); dp[7] = bf2f(v.w >> 16);
    }
  } else {
    const float* A = (const float*)Ap;
    for (int i = t; i < 128 * (K / 4); i += 256) {
      int rr = i / (K / 4), cc = i % (K / 4);
      float4 v = (r0 + rr < NE) ? ((const float4*)(A + (size_t)(r0 + rr) * K))[cc]
                                : make_float4(0.f, 0.f, 0.f, 0.f);
      sA[rr][cc * 4 + 0] = v.x;
      sA[rr][cc * 4 + 1] = v.y;
      sA[rr][cc * 4 + 2] = v.z;
      sA[rr][cc * 4 + 3] = v.w;
    }
  }
  __syncthreads();
  int rg = t >> 3, cg = t & 7;
  float acc[4][8];
#pragma unroll
  for (int i = 0; i < 4; ++i)
#pragma unroll
    for (int j = 0; j < 8; ++j) acc[i][j] = 0.f;
#pragma unroll 8
  for (int k = 0; k < K; ++k) {
    float a0 = sA[rg * 4 + 0][k], a1 = sA[rg * 4 + 1][k];
    float a2 = sA[rg * 4 + 2][k], a3 = sA[rg * 4 + 3][k];
    float4 wA = *(const float4*)&sW[k][cg * 8];
    float4 wB = *(const float4*)&sW[k][cg * 8 + 4];
#pragma unroll
    for (int i = 0; i < 4; ++i) {
      float a = i == 0 ? a0 : i == 1 ? a1 : i == 2 ? a2 : a3;
      acc[i][0] = fmaf(a, wA.x, acc[i][0]); acc[i][1] = fmaf(a, wA.y, acc[i][1]);
      acc[i][2] = fmaf(a, wA.z, acc[i][2]); acc[i][3] = fmaf(a, wA.w, acc[i][3]);
      acc[i][4] = fmaf(a, wB.x, acc[i][4]); acc[i][5] = fmaf(a, wB.y, acc[i][5]);
      acc[i][6] = fmaf(a, wB.z, acc[i][6]); acc[i][7] = fmaf(a, wB.w, acc[i][7]);
    }
  }
  float bv[8], av[8];
#pragma unroll
  for (int j = 0; j < 8; ++j) {
    bv[j] = bias[cg * 8 + j];
    av[j] = attn[cg * 8 + j];
  }
#pragma unroll
  for (int i = 0; i < 4; ++i) {
    int r = r0 + rg * 4 + i;
    if (r < NE) {
      int s = src_s[r], d = dst_s[r];
      uint4 hv = *(const uint4*)(hs + (size_t)s * 64 + cg * 8);
      uint4 dv = *(const uint4*)(hd + (size_t)d * 64 + cg * 8);
      float fo[8];
      fo[0] = acc[i][0] + bf2f(hv.x & 0xffff) + bf2f(dv.x & 0xffff) + bv[0];
      fo[1] = acc[i][1] + bf2f(hv.x >> 16)    + bf2f(dv.x >> 16)    + bv[1];
      fo[2] = acc[i][2] + bf2f(hv.y & 0xffff) + bf2f(dv.y & 0xffff) + bv[2];
      fo[3] = acc[i][3] + bf2f(hv.y >> 16)    + bf2f(dv.y >> 16)    + bv[3];
      fo[4] = acc[i][4] + bf2f(hv.z & 0xffff) + bf2f(dv.z & 0xffff) + bv[4];
      fo[5] = acc[i][5] + bf2f(hv.z >> 16)    + bf2f(dv.z >> 16)    + bv[5];
      fo[6] = acc[i][6] + bf2f(hv.w & 0xffff) + bf2f(dv.w & 0xffff) + bv[6];
      fo[7] = acc[i][7] + bf2f(hv.w >> 16)    + bf2f(dv.w >> 16)    + bv[7];
      float p = 0.f;
#pragma unroll
      for (int j = 0; j < 8; ++j) {
        fo[j] = fo[j] >= 0.f ? fo[j] : 0.01f * fo[j];  // LeakyReLU
        p = fmaf(fo[j], av[j], p);
      }
      if (STORE) {
        uint4 pv;
        pv.x = pack2(fo[0], fo[1]);
        pv.y = pack2(fo[2], fo[3]);
        pv.z = pack2(fo[4], fo[5]);
        pv.w = pack2(fo[6], fo[7]);
        *(uint4*)(fstore + (size_t)r * 64 + cg * 8) = pv;
      }
      p += __shfl_xor(p, 1, 64);
      p += __shfl_xor(p, 2, 64);
      p += __shfl_xor(p, 4, 64);
      if (cg == 0) logit[r] = p;
    }
  }
}

// ---------------- EGAT: gather-aggregate, no max pre-pass (logits ~O(1), exp f32-safe) ---
__global__ __launch_bounds__(256, 4) void agg_gather_kernel(
    const ush* __restrict__ hn, const float* __restrict__ logit, const int* __restrict__ rowptr,
    const int* __restrict__ deg, const int* __restrict__ src_s, float* __restrict__ hnew) {
  int wave = (blockIdx.x * blockDim.x + threadIdx.x) >> 6;
  int lane = threadIdx.x & 63;
  if (wave >= NN) return;
  int n = wave, d = deg[n], r0 = rowptr[n];
  if (d == 0) {
    hnew[(size_t)n * 64 + lane] = 0.f;
    return;
  }
  float sum = 0.f, acc0 = 0.f, acc1 = 0.f, acc2 = 0.f, acc3 = 0.f;
  int j = 0;
  for (; j + 3 < d; j += 4) {
    int jj = r0 + j;
    int s0 = src_s[jj + 0], s1 = src_s[jj + 1], s2 = src_s[jj + 2], s3 = src_s[jj + 3];
    float l0 = logit[jj + 0], l1 = logit[jj + 1], l2 = logit[jj + 2], l3 = logit[jj + 3];
    ush h0 = hn[(size_t)s0 * 64 + lane];
    ush h1 = hn[(size_t)s1 * 64 + lane];
    ush h2 = hn[(size_t)s2 * 64 + lane];
    ush h3 = hn[(size_t)s3 * 64 + lane];
    float w0 = __expf(l0), w1 = __expf(l1);
    float w2 = __expf(l2), w3 = __expf(l3);
    sum += (w0 + w1) + (w2 + w3);
    acc0 = fmaf(w0, bf2f(h0), acc0);
    acc1 = fmaf(w1, bf2f(h1), acc1);
    acc2 = fmaf(w2, bf2f(h2), acc2);
    acc3 = fmaf(w3, bf2f(h3), acc3);
  }
  for (; j < d; ++j) {
    int jj = r0 + j;
    float w = __expf(logit[jj]);
    sum += w;
    acc0 = fmaf(w, bf2f(hn[(size_t)src_s[jj] * 64 + lane]), acc0);
  }
  hnew[(size_t)n * 64 + lane] = ((acc0 + acc1) + (acc2 + acc3)) / sum;
}

// ---------------- NNConv stage 2 (gather, 4-deep load-then-FMA pipeline) -----------------
__global__ __launch_bounds__(256, 4) void nnconv_gather_kernel(
    const ush* __restrict__ z, const float* __restrict__ q, const float* __restrict__ ef_s,
    const int* __restrict__ rowptr, const int* __restrict__ deg, const int* __restrict__ src_s,
    float* __restrict__ sArr) {
  int wave = (blockIdx.x * blockDim.x + threadIdx.x) >> 6;
  int lane = threadIdx.x & 63;
  if (wave >= NN) return;
  int n = wave, d = deg[n], r0 = rowptr[n];
  int o = lane >> 1, half = lane & 1;
  float acc0 = 0.f, acc1 = 0.f, acc2 = 0.f, acc3 = 0.f;
  int j = 0;
  for (; j + 3 < d; j += 4) {
    int jj = r0 + j;
    int s0 = src_s[jj + 0], s1 = src_s[jj + 1], s2 = src_s[jj + 2], s3 = src_s[jj + 3];
    uint4 zv0 = *(const uint4*)(z + (size_t)s0 * 512 + lane * 8);
    uint4 zv1 = *(const uint4*)(z + (size_t)s1 * 512 + lane * 8);
    uint4 zv2 = *(const uint4*)(z + (size_t)s2 * 512 + lane * 8);
    uint4 zv3 = *(const uint4*)(z + (size_t)s3 * 512 + lane * 8);
    const float4* ep0 = (const float4*)(ef_s + (size_t)(jj + 0) * 16 + half * 8);
    const float4* ep1 = (const float4*)(ef_s + (size_t)(jj + 1) * 16 + half * 8);
    const float4* ep2 = (const float4*)(ef_s + (size_t)(jj + 2) * 16 + half * 8);
    const float4* ep3 = (const float4*)(ef_s + (size_t)(jj + 3) * 16 + half * 8);
    float4 ea0 = ep0[0], eb0 = ep0[1];
    float4 ea1 = ep1[0], eb1 = ep1[1];
    float4 ea2 = ep2[0], eb2 = ep2[1];
    float4 ea3 = ep3[0], eb3 = ep3[1];
    float q0 = 0.f, q1 = 0.f, q2 = 0.f, q3 = 0.f;
    if (half == 0) {
      q0 = q[(size_t)s0 * 32 + o];
      q1 = q[(size_t)s1 * 32 + o];
      q2 = q[(size_t)s2 * 32 + o];
      q3 = q[(size_t)s3 * 32 + o];
    }
    acc0 += dot8(ea0, eb0, zv0) + q0;
    acc1 += dot8(ea1, eb1, zv1) + q1;
    acc2 += dot8(ea2, eb2, zv2) + q2;
    acc3 += dot8(ea3, eb3, zv3) + q3;
  }
  for (; j < d; ++j) {
    int jj = r0 + j;
    int s = src_s[jj];
    const float4* ep = (const float4*)(ef_s + (size_t)jj * 16 + half * 8);
    float4 ea = ep[0], eb = ep[1];
    uint4 zv = *(const uint4*)(z + (size_t)s * 512 + lane * 8);
    float qv = (half == 0) ? q[(size_t)s * 32 + o] : 0.f;
    acc0 += dot8(ea, eb, zv) + qv;
  }
  float acc = (acc0 + acc1) + (acc2 + acc3);
  acc += __shfl_xor(acc, 1, 64);
  if (half == 0) sArr[(size_t)n * 32 + o] = acc;
}

// ---------------- combine node_features + gate logit (fused; wave per node) --------------
__global__ void combine_gate_kernel(const float* __restrict__ hfin, const float* __restrict__ sArr,
                                    const int* __restrict__ deg, const float* __restrict__ nn_bias,
                                    const float* __restrict__ gate_w, const float* __restrict__ gate_b,
                                    float* __restrict__ out, float* __restrict__ g) {
  int wave = (blockIdx.x * blockDim.x + threadIdx.x) >> 6;
  int lane = threadIdx.x & 63;
  if (wave >= NN) return;
  int n = wave;
  float v0 = hfin[(size_t)n * 64 + lane];
  int c1 = lane + 64;
  float v1 = (c1 < 96)
                 ? sArr[(size_t)n * 32 + (c1 - 64)] / fmaxf((float)deg[n], 1.0f) + nn_bias[c1 - 64]
                 : 0.f;
  out[(size_t)n * 128 + lane] = v0;
  out[(size_t)n * 128 + c1] = v1;
  float p = v0 * gate_w[lane] + ((c1 < 96) ? v1 * gate_w[c1] : 0.f);
#pragma unroll
  for (int off = 32; off; off >>= 1) p += __shfl_xor(p, off, 64);
  if (lane == 0) g[n] = p + gate_b[0];
}

// ---------------- max over g (block-reduced, 1 atomic per block) ----------------
__global__ void gate_max_kernel(const float* __restrict__ g, unsigned* __restrict__ gmax) {
  int tid = blockIdx.x * blockDim.x + threadIdx.x;
  int stride = gridDim.x * blockDim.x;
  float v = -3.0e38f;
  for (int n = tid; n < NN; n += stride) v = fmaxf(v, g[n]);
#pragma unroll
  for (int off = 32; off; off >>= 1) v = fmaxf(v, __shfl_xor(v, off, 64));
  __shared__ float sm[4];
  int lane = threadIdx.x & 63, wid = threadIdx.x >> 6;
  if (lane == 0) sm[wid] = v;
  __syncthreads();
  if (threadIdx.x == 0) {
    float m = fmaxf(fmaxf(sm[0], sm[1]), fmaxf(sm[2], sm[3]));
    atomicMax(gmax, ord_enc(m));
  }
}

// ---------------- pooling: exp + weighted accumulate (fused) ----------------
__global__ void pool_exp_kernel(const float* __restrict__ nf, const float* __restrict__ g,
                                const unsigned* __restrict__ gmax, float* __restrict__ gacc,
                                float* __restrict__ gsum) {
  int o = threadIdx.x;  // blockDim = 128
  float m = ord_dec(*gmax);
  float acc = 0.f, ws = 0.f;
  for (int n = blockIdx.x; n < NN; n += gridDim.x) {
    float w = __expf(g[n] - m);
    ws += w;
    acc += w * nf[(size_t)n * 128 + o];
  }
  atomicAdd(gacc + o, acc);
  if (o == 0) atomicAdd(gsum, ws);
}

__global__ void finalize_kernel(const float* __restrict__ gacc, const float* __restrict__ gsum,
                                float* __restrict__ out) {
  int o = threadIdx.x;
  if (o < 128) out[(size_t)NN * 128 + o] = gacc[o] / gsum[0];
}

extern "C" void kernel_launch(void* const* d_in, const int* in_sizes, int n_in,
                              void* d_out, int out_size, void* d_ws, size_t ws_size,
                              hipStream_t stream) {
  const float* face    = (const float*)d_in[0];
  const float* ef      = (const float*)d_in[1];
  const float* fp_w    = (const float*)d_in[2];
  const float* fp_b    = (const float*)d_in[3];
  const float* ep_w    = (const float*)d_in[4];
  const float* ep_b    = (const float*)d_in[5];
  const float* nn_w    = (const float*)d_in[6];
  const float* nn_b    = (const float*)d_in[7];
  const float* nn_bias = (const float*)d_in[8];
  const float* gate_w  = (const float*)d_in[9];
  const float* gate_b  = (const float*)d_in[10];
  const int*   src     = (const int*)d_in[11];
  const int*   dst     = (const int*)d_in[12];
  const float* e1_attn = (const float*)d_in[17];
  const float* e2_ni   = (const float*)d_in[19];
  const float* e2_nj   = (const float*)d_in[20];
  const float* e2_fij  = (const float*)d_in[21];
  const float* e2_node = (const float*)d_in[22];
  const float* e2_attn = (const float*)d_in[23];
  const float* e2_bias = (const float*)d_in[24];
  float* out = (float*)d_out;

  char* p = (char*)d_ws;
  auto alloc = [&](size_t nfloats) {
    float* r = (float*)p;
    p += ((nfloats * 4 + 255) / 256) * 256;
    return r;
  };
  float* h0 = alloc((size_t)NN * 64);   // layer-2 output
  float* h1 = alloc((size_t)NN * 64);   // layer-1 output; q aliases after EGAT
  char* regionC = p;                    // hs16|hd16|hn16|f116 = 61.4 MB, dead after EGAT
  ush* hs16 = (ush*)alloc((size_t)NN * 32);   // NN*64 bf16
  ush* hd16 = (ush*)alloc((size_t)NN * 32);
  ush* hn16 = (ush*)alloc((size_t)NN * 32);
  ush* f116 = (ush*)alloc((size_t)NE * 32);   // NE*64 bf16 (dst-sorted order)
  float* logit = alloc(NE);                   // dst-sorted order
  float* sArr  = alloc((size_t)NN * 32);
  float* g     = alloc(NN);
  float* gacc  = alloc(128);
  float* gsum  = alloc(1);
  unsigned* gmax = (unsigned*)alloc(1);
  float* fold  = alloc(7424);
  float* W2    = alloc(32 * 576);
  // dst-CSR
  int* deg    = (int*)alloc(NN);
  int* rowptr = (int*)alloc(NN);
  int* cursor = (int*)alloc(NN);
  int* partial = (int*)alloc(256);
  int* src_s  = (int*)alloc(NE);
  int* dst_s  = (int*)alloc(NE);
  int* eid_s  = (int*)alloc(NE);
  float* ef_s = alloc((size_t)NE * 16);       // permuted edge features
  ush* z16 = (ush*)regionC;             // NN*512 bf16 = 61.44 MB == regionC exactly
  float* q = h1;                        // NN*32 <= h1's NN*64, h1 dead post-EGAT

  const float* Wf1  = fold;
  const float* b1f  = fold + 1024;
  const float* Wni1 = fold + 1088;
  const float* Wnj1 = fold + 3136;
  const float* Wno1 = fold + 5184;
  const float* bni1 = fold + 7232;
  const float* bnj1 = fold + 7296;
  const float* bno1 = fold + 7360;

  const int B = 256;
  const int NGB = cdiv(NN, 128);
  const int EGB = cdiv(NE, 128);
  const int NB256 = cdiv(NN, 256);

  // ---- CSR build (dst-sorted) + edge permutation ----
  hipMemsetAsync(deg, 0, NN * 4, stream);
  deg_kernel<<<cdiv(NE, B), B, 0, stream>>>(dst, deg);
  scan1_kernel<<<NB256, 256, 0, stream>>>(deg, rowptr, partial);
  scan2_kernel<<<1, 256, 0, stream>>>(partial, NB256);
  scan3_kernel<<<NB256, 256, 0, stream>>>(rowptr, partial, cursor);
  scatter_dst_kernel<<<cdiv(NE, B), B, 0, stream>>>(src, dst, cursor, src_s, dst_s, eid_s);
  permute_ef_kernel<<<cdiv(NE * 4, B), B, 0, stream>>>(ef, eid_s, ef_s);

  // folded weights + nn_w transpose (tiny)
  fold_kernel<<<29, B, 0, stream>>>(fp_w, fp_b, ep_w, ep_b,
                                    (const float*)d_in[15], (const float*)d_in[18],
                                    (const float*)d_in[13], (const float*)d_in[14],
                                    (const float*)d_in[16], fold);
  nnwt_kernel<<<72, B, 0, stream>>>(nn_w, nn_b, W2);

  // ---- EGAT layer 1 (edges processed in dst-sorted order) ----
  gemm3_kernel<32, true><<<dim3(NGB, 3), B, 0, stream>>>(face, Wni1, Wnj1, Wno1, bni1, bnj1,
                                                         bno1, hs16, hd16, hn16, NN);
  gemm_fout_kernel<16, true, false><<<EGB, B, 0, stream>>>(ef_s, Wf1, b1f, hs16, hd16, src_s,
                                                           dst_s, e1_attn, f116, logit);
  agg_gather_kernel<<<cdiv(NN * 64, B), B, 0, stream>>>(hn16, logit, rowptr, deg, src_s, h1);

  // ---- EGAT layer 2 ----
  gemm3_kernel<64, false><<<dim3(NGB, 3), B, 0, stream>>>(h1, e2_ni, e2_nj, e2_node, nullptr,
                                                          nullptr, nullptr, hs16, hd16, hn16, NN);
  gemm_fout_kernel<64, false, true><<<EGB, B, 0, stream>>>(f116, e2_fij, e2_bias, hs16, hd16,
                                                           src_s, dst_s, e2_attn, nullptr, logit);
  agg_gather_kernel<<<cdiv(NN * 64, B), B, 0, stream>>>(hn16, logit, rowptr, deg, src_s, h0);

  // ---- NNConv (z16/q alias dead EGAT buffers — must run after EGAT) ----
  gemm_zq_kernel<<<dim3(NGB, 9), B, 0, stream>>>(face, W2, z16, q, NN);
  nnconv_gather_kernel<<<cdiv(NN * 64, B), B, 0, stream>>>(z16, q, ef_s, rowptr, deg, src_s,
                                                           sArr);

  // ---- combine node features + gate logits ----
  hipMemsetAsync(gacc, 0, 128 * 4, stream);
  hipMemsetAsync(gsum, 0, 4, stream);
  hipMemsetAsync(gmax, 0, 4, stream);
  combine_gate_kernel<<<cdiv(NN * 64, B), B, 0, stream>>>(h0, sArr, deg, nn_bias, gate_w,
                                                          gate_b, out, g);
  gate_max_kernel<<<128, B, 0, stream>>>(g, gmax);
  pool_exp_kernel<<<512, 128, 0, stream>>>(out, g, gmax, gacc, gsum);
  finalize_kernel<<<1, 128, 0, stream>>>(gacc, gsum, out);
}

// Round 16
// 372.951 us; speedup vs baseline: 1.2785x; 1.0595x over previous
//
#include <hip/hip_runtime.h>

#define NN 60000
#define NE 300000
typedef unsigned short ush;

static inline int cdiv(int a, int b) { return (a + b - 1) / b; }

__device__ inline unsigned ord_enc(float x) {
  unsigned u = __float_as_uint(x);
  return (u & 0x80000000u) ? ~u : (u | 0x80000000u);
}
__device__ inline float ord_dec(unsigned u) {
  return __uint_as_float((u & 0x80000000u) ? (u & 0x7fffffffu) : ~u);
}
__device__ inline float bf2f(unsigned u16) { return __uint_as_float(u16 << 16); }
__device__ inline ush f2bf(float x) {
  unsigned u = __float_as_uint(x);
  return (ush)((u + 0x7FFFu + ((u >> 16) & 1u)) >> 16);
}
__device__ inline unsigned pack2(float lo, float hi) {
  return ((unsigned)f2bf(hi) << 16) | (unsigned)f2bf(lo);
}

// ================= CSR build (dst-sorted) =================
__global__ void deg_kernel(const int* __restrict__ key, int* __restrict__ deg) {
  int e = blockIdx.x * blockDim.x + threadIdx.x;
  if (e < NE) atomicAdd(deg + key[e], 1);
}

__global__ void scan1_kernel(const int* __restrict__ deg, int* __restrict__ rowptr,
                             int* __restrict__ partial) {
  __shared__ int s[256];
  int i = blockIdx.x * 256 + threadIdx.x;
  int v = (i < NN) ? deg[i] : 0;
  s[threadIdx.x] = v;
  __syncthreads();
  for (int off = 1; off < 256; off <<= 1) {
    int t = (threadIdx.x >= off) ? s[threadIdx.x - off] : 0;
    __syncthreads();
    s[threadIdx.x] += t;
    __syncthreads();
  }
  if (i < NN) rowptr[i] = s[threadIdx.x] - v;
  if (threadIdx.x == 255) partial[blockIdx.x] = s[255];
}

__global__ void scan2_kernel(int* __restrict__ partial, int nb) {
  __shared__ int s[256];
  int v = (threadIdx.x < nb) ? partial[threadIdx.x] : 0;
  s[threadIdx.x] = v;
  __syncthreads();
  for (int off = 1; off < 256; off <<= 1) {
    int t = (threadIdx.x >= off) ? s[threadIdx.x - off] : 0;
    __syncthreads();
    s[threadIdx.x] += t;
    __syncthreads();
  }
  if (threadIdx.x < nb) partial[threadIdx.x] = s[threadIdx.x] - v;
}

__global__ void scan3_kernel(int* __restrict__ rowptr, const int* __restrict__ partial,
                             int* __restrict__ cursor) {
  int i = blockIdx.x * 256 + threadIdx.x;
  if (i < NN) {
    int r = rowptr[i] + partial[blockIdx.x];
    rowptr[i] = r;
    cursor[i] = r;
  }
}

// scatter + ef permutation fused (sequential ef read, random 64B write)
__global__ void scatter_dst_kernel(const int* __restrict__ src, const int* __restrict__ dst,
                                   const float* __restrict__ ef, int* __restrict__ cursor,
                                   int* __restrict__ src_s, int* __restrict__ dst_s,
                                   float* __restrict__ ef_s) {
  int e = blockIdx.x * blockDim.x + threadIdx.x;
  if (e >= NE) return;
  int d = dst[e];
  int j = atomicAdd(cursor + d, 1);
  src_s[j] = src[e];
  dst_s[j] = d;
  const float4* ep = (const float4*)(ef + (size_t)e * 16);
  float4 a = ep[0], b = ep[1], c = ep[2], dd = ep[3];
  float4* op = (float4*)(ef_s + (size_t)j * 16);
  op[0] = a; op[1] = b; op[2] = c; op[3] = dd;
}

// ---------------- fold: precompute folded weight products (7424 dots of length 64) -------
__global__ void fold_kernel(const float* __restrict__ fp_w, const float* __restrict__ fp_b,
                            const float* __restrict__ ep_w, const float* __restrict__ ep_b,
                            const float* __restrict__ fij, const float* __restrict__ ebias,
                            const float* __restrict__ ni, const float* __restrict__ nj,
                            const float* __restrict__ node, float* __restrict__ fold) {
  int t = blockIdx.x * blockDim.x + threadIdx.x;
  if (t >= 7424) return;
  int o = t & 63;
  const float* A;
  const float* B;
  float init = 0.f;
  if (t < 1024)      { A = ep_w + (size_t)(t >> 6) * 64; B = fij + o; }
  else if (t < 1088) { A = ep_b; B = fij + o; init = ebias[o]; }
  else if (t < 3136) { A = fp_w + (size_t)((t - 1088) >> 6) * 64; B = ni + o; }
  else if (t < 5184) { A = fp_w + (size_t)((t - 3136) >> 6) * 64; B = nj + o; }
  else if (t < 7232) { A = fp_w + (size_t)((t - 5184) >> 6) * 64; B = node + o; }
  else if (t < 7296) { A = fp_b; B = ni + o; }
  else if (t < 7360) { A = fp_b; B = nj + o; }
  else               { A = fp_b; B = node + o; }
  float a = init;
  for (int i = 0; i < 64; ++i) a = fmaf(A[i], B[(size_t)i * 64], a);
  fold[t] = a;
}

// ---------------- pack nn_w/nn_b -> bf16 W2bf[544][32]: c=k*32+i -> nn_w[k][i*32+o],
//                  c=512+i -> nn_b[i*32+o] ----------------
__global__ void nnwt_kernel(const float* __restrict__ nn_w, const float* __restrict__ nn_b,
                            ush* __restrict__ W2bf) {
  int t = blockIdx.x * blockDim.x + threadIdx.x;
  if (t >= 544 * 32) return;
  int c = t >> 5, o = t & 31;
  float v;
  if (c < 512) {
    int k = c >> 5, i = c & 31;
    v = nn_w[(size_t)k * 1024 + i * 32 + o];
  } else {
    v = nn_b[(c - 512) * 32 + o];
  }
  W2bf[t] = f2bf(v);
}

// ---------------- tiled GEMM (rows x K) @ (K x 64) -> bf16 out; 3 weight sets ------------
template <int K, bool BIAS>
__global__ __launch_bounds__(256, 2) void gemm3_kernel(
    const float* __restrict__ A, const float* __restrict__ W0, const float* __restrict__ W1,
    const float* __restrict__ W2, const float* __restrict__ b0, const float* __restrict__ b1,
    const float* __restrict__ b2, ush* __restrict__ o0, ush* __restrict__ o1,
    ush* __restrict__ o2, int rows) {
  __shared__ float sA[128][K + 1];
  __shared__ float sW[K][64];
  const float* W = blockIdx.y == 0 ? W0 : blockIdx.y == 1 ? W1 : W2;
  const float* bb = blockIdx.y == 0 ? b0 : blockIdx.y == 1 ? b1 : b2;
  ush* out = blockIdx.y == 0 ? o0 : blockIdx.y == 1 ? o1 : o2;
  int t = threadIdx.x;
  int r0 = blockIdx.x * 128;
  for (int i = t; i < K * 16; i += 256) ((float4*)sW)[i] = ((const float4*)W)[i];
  for (int i = t; i < 128 * (K / 4); i += 256) {
    int rr = i / (K / 4), cc = i % (K / 4);
    float4 v = (r0 + rr < rows) ? ((const float4*)(A + (size_t)(r0 + rr) * K))[cc]
                                : make_float4(0.f, 0.f, 0.f, 0.f);
    sA[rr][cc * 4 + 0] = v.x;
    sA[rr][cc * 4 + 1] = v.y;
    sA[rr][cc * 4 + 2] = v.z;
    sA[rr][cc * 4 + 3] = v.w;
  }
  __syncthreads();
  int rg = t >> 3, cg = t & 7;
  float acc[4][8];
#pragma unroll
  for (int i = 0; i < 4; ++i)
#pragma unroll
    for (int j = 0; j < 8; ++j) acc[i][j] = 0.f;
#pragma unroll 8
  for (int k = 0; k < K; ++k) {
    float a0 = sA[rg * 4 + 0][k], a1 = sA[rg * 4 + 1][k];
    float a2 = sA[rg * 4 + 2][k], a3 = sA[rg * 4 + 3][k];
    float4 wA = *(const float4*)&sW[k][cg * 8];
    float4 wB = *(const float4*)&sW[k][cg * 8 + 4];
#pragma unroll
    for (int i = 0; i < 4; ++i) {
      float a = i == 0 ? a0 : i == 1 ? a1 : i == 2 ? a2 : a3;
      acc[i][0] = fmaf(a, wA.x, acc[i][0]); acc[i][1] = fmaf(a, wA.y, acc[i][1]);
      acc[i][2] = fmaf(a, wA.z, acc[i][2]); acc[i][3] = fmaf(a, wA.w, acc[i][3]);
      acc[i][4] = fmaf(a, wB.x, acc[i][4]); acc[i][5] = fmaf(a, wB.y, acc[i][5]);
      acc[i][6] = fmaf(a, wB.z, acc[i][6]); acc[i][7] = fmaf(a, wB.w, acc[i][7]);
    }
  }
  float bv[8];
#pragma unroll
  for (int j = 0; j < 8; ++j) bv[j] = BIAS ? bb[cg * 8 + j] : 0.f;
#pragma unroll
  for (int i = 0; i < 4; ++i) {
    int r = r0 + rg * 4 + i;
    if (r < rows) {
      uint4 pv;
      pv.x = pack2(acc[i][0] + bv[0], acc[i][1] + bv[1]);
      pv.y = pack2(acc[i][2] + bv[2], acc[i][3] + bv[3]);
      pv.z = pack2(acc[i][4] + bv[4], acc[i][5] + bv[5]);
      pv.w = pack2(acc[i][6] + bv[6], acc[i][7] + bv[7]);
      *(uint4*)(out + (size_t)r * 64 + cg * 8) = pv;
    }
  }
}

// ---------------- edge GEMM + fused f_out epilogue (edges in dst-sorted order) -----------
template <int K, bool STORE, bool ABF>
__global__ __launch_bounds__(256, 2) void gemm_fout_kernel(
    const void* __restrict__ Ap, const float* __restrict__ W, const float* __restrict__ bias,
    const ush* __restrict__ hs, const ush* __restrict__ hd, const int* __restrict__ src_s,
    const int* __restrict__ dst_s, const float* __restrict__ attn, ush* __restrict__ fstore,
    float* __restrict__ logit) {
  __shared__ float sA[128][K + 1];
  __shared__ float sW[K][64];
  int t = threadIdx.x;
  int r0 = blockIdx.x * 128;
  for (int i = t; i < K * 16; i += 256) ((float4*)sW)[i] = ((const float4*)W)[i];
  if (ABF) {
    const ush* A = (const ush*)Ap;
    for (int i = t; i < 128 * (K / 8); i += 256) {
      int rr = i / (K / 8), cc = i % (K / 8);
      uint4 v = (r0 + rr < NE) ? ((const uint4*)(A + (size_t)(r0 + rr) * K))[cc]
                               : make_uint4(0, 0, 0, 0);
      float* dp = &sA[rr][cc * 8];
      dp[0] = bf2f(v.x & 0xffff); dp[1] = bf2f(v.x >> 16);
      dp[2] = bf2f(v.y & 0xffff); dp[3] = bf2f(v.y >> 16);
      dp[4] = bf2f(v.z & 0xffff); dp[5] = bf2f(v.z >> 16);
      dp[6] = bf2f(v.w & 0xffff); dp[7] = bf2f(v.w >> 16);
    }
  } else {
    const float* A = (const float*)Ap;
    for (int i = t; i < 128 * (K / 4); i += 256) {
      int rr = i / (K / 4), cc = i % (K / 4);
      float4 v = (r0 + rr < NE) ? ((const float4*)(A + (size_t)(r0 + rr) * K))[cc]
                                : make_float4(0.f, 0.f, 0.f, 0.f);
      sA[rr][cc * 4 + 0] = v.x;
      sA[rr][cc * 4 + 1] = v.y;
      sA[rr][cc * 4 + 2] = v.z;
      sA[rr][cc * 4 + 3] = v.w;
    }
  }
  __syncthreads();
  int rg = t >> 3, cg = t & 7;
  float acc[4][8];
#pragma unroll
  for (int i = 0; i < 4; ++i)
#pragma unroll
    for (int j = 0; j < 8; ++j) acc[i][j] = 0.f;
#pragma unroll 8
  for (int k = 0; k < K; ++k) {
    float a0 = sA[rg * 4 + 0][k], a1 = sA[rg * 4 + 1][k];
    float a2 = sA[rg * 4 + 2][k], a3 = sA[rg * 4 + 3][k];
    float4 wA = *(const float4*)&sW[k][cg * 8];
    float4 wB = *(const float4*)&sW[k][cg * 8 + 4];
#pragma unroll
    for (int i = 0; i < 4; ++i) {
      float a = i == 0 ? a0 : i == 1 ? a1 : i == 2 ? a2 : a3;
      acc[i][0] = fmaf(a, wA.x, acc[i][0]); acc[i][1] = fmaf(a, wA.y, acc[i][1]);
      acc[i][2] = fmaf(a, wA.z, acc[i][2]); acc[i][3] = fmaf(a, wA.w, acc[i][3]);
      acc[i][4] = fmaf(a, wB.x, acc[i][4]); acc[i][5] = fmaf(a, wB.y, acc[i][5]);
      acc[i][6] = fmaf(a, wB.z, acc[i][6]); acc[i][7] = fmaf(a, wB.w, acc[i][7]);
    }
  }
  float bv[8], av[8];
#pragma unroll
  for (int j = 0; j < 8; ++j) {
    bv[j] = bias[cg * 8 + j];
    av[j] = attn[cg * 8 + j];
  }
#pragma unroll
  for (int i = 0; i < 4; ++i) {
    int r = r0 + rg * 4 + i;
    if (r < NE) {
      int s = src_s[r], d = dst_s[r];
      uint4 hv = *(const uint4*)(hs + (size_t)s * 64 + cg * 8);
      uint4 dv = *(const uint4*)(hd + (size_t)d * 64 + cg * 8);
      float fo[8];
      fo[0] = acc[i][0] + bf2f(hv.x & 0xffff) + bf2f(dv.x & 0xffff) + bv[0];
      fo[1] = acc[i][1] + bf2f(hv.x >> 16)    + bf2f(dv.x >> 16)    + bv[1];
      fo[2] = acc[i][2] + bf2f(hv.y & 0xffff) + bf2f(dv.y & 0xffff) + bv[2];
      fo[3] = acc[i][3] + bf2f(hv.y >> 16)    + bf2f(dv.y >> 16)    + bv[3];
      fo[4] = acc[i][4] + bf2f(hv.z & 0xffff) + bf2f(dv.z & 0xffff) + bv[4];
      fo[5] = acc[i][5] + bf2f(hv.z >> 16)    + bf2f(dv.z >> 16)    + bv[5];
      fo[6] = acc[i][6] + bf2f(hv.w & 0xffff) + bf2f(dv.w & 0xffff) + bv[6];
      fo[7] = acc[i][7] + bf2f(hv.w >> 16)    + bf2f(dv.w >> 16)    + bv[7];
      float p = 0.f;
#pragma unroll
      for (int j = 0; j < 8; ++j) {
        fo[j] = fo[j] >= 0.f ? fo[j] : 0.01f * fo[j];  // LeakyReLU
        p = fmaf(fo[j], av[j], p);
      }
      if (STORE) {
        uint4 pv;
        pv.x = pack2(fo[0], fo[1]);
        pv.y = pack2(fo[2], fo[3]);
        pv.z = pack2(fo[4], fo[5]);
        pv.w = pack2(fo[6], fo[7]);
        *(uint4*)(fstore + (size_t)r * 64 + cg * 8) = pv;
      }
      p += __shfl_xor(p, 1, 64);
      p += __shfl_xor(p, 2, 64);
      p += __shfl_xor(p, 4, 64);
      if (cg == 0) logit[r] = p;
    }
  }
}

// ---------------- EGAT: gather-aggregate, no max pre-pass (logits ~O(1), exp f32-safe) ---
__global__ __launch_bounds__(256, 4) void agg_gather_kernel(
    const ush* __restrict__ hn, const float* __restrict__ logit, const int* __restrict__ rowptr,
    const int* __restrict__ deg, const int* __restrict__ src_s, float* __restrict__ hnew) {
  int wave = (blockIdx.x * blockDim.x + threadIdx.x) >> 6;
  int lane = threadIdx.x & 63;
  if (wave >= NN) return;
  int n = wave, d = deg[n], r0 = rowptr[n];
  if (d == 0) {
    hnew[(size_t)n * 64 + lane] = 0.f;
    return;
  }
  float sum = 0.f, acc0 = 0.f, acc1 = 0.f, acc2 = 0.f, acc3 = 0.f;
  int j = 0;
  for (; j + 3 < d; j += 4) {
    int jj = r0 + j;
    int s0 = src_s[jj + 0], s1 = src_s[jj + 1], s2 = src_s[jj + 2], s3 = src_s[jj + 3];
    float l0 = logit[jj + 0], l1 = logit[jj + 1], l2 = logit[jj + 2], l3 = logit[jj + 3];
    ush h0 = hn[(size_t)s0 * 64 + lane];
    ush h1 = hn[(size_t)s1 * 64 + lane];
    ush h2 = hn[(size_t)s2 * 64 + lane];
    ush h3 = hn[(size_t)s3 * 64 + lane];
    float w0 = __expf(l0), w1 = __expf(l1);
    float w2 = __expf(l2), w3 = __expf(l3);
    sum += (w0 + w1) + (w2 + w3);
    acc0 = fmaf(w0, bf2f(h0), acc0);
    acc1 = fmaf(w1, bf2f(h1), acc1);
    acc2 = fmaf(w2, bf2f(h2), acc2);
    acc3 = fmaf(w3, bf2f(h3), acc3);
  }
  for (; j < d; ++j) {
    int jj = r0 + j;
    float w = __expf(logit[jj]);
    sum += w;
    acc0 = fmaf(w, bf2f(hn[(size_t)src_s[jj] * 64 + lane]), acc0);
  }
  hnew[(size_t)n * 64 + lane] = ((acc0 + acc1) + (acc2 + acc3)) / sum;
}

// ---------------- NNConv phase A: per-node outer-product G accumulate (registers only) ---
// G[n][c]: c = k*32+i (k<16) = sum_{e->n} ef_s[e][k]*face[src][i]; c=512+i = Fsum[i].
// lane owns k=lane>>2, i in [(lane&3)*8, +8). Row write fully coalesced (c = lane*8).
__global__ __launch_bounds__(256, 4) void nnconv_G_kernel(
    const float* __restrict__ face, const float* __restrict__ ef_s,
    const int* __restrict__ rowptr, const int* __restrict__ deg, const int* __restrict__ src_s,
    ush* __restrict__ G) {
  int wave = (blockIdx.x * blockDim.x + threadIdx.x) >> 6;
  int lane = threadIdx.x & 63;
  if (wave >= NN) return;
  int n = wave, d = deg[n], r0 = rowptr[n];
  int k4 = lane >> 2, ib = lane & 3;
  float g[8], fs[8];
#pragma unroll
  for (int u = 0; u < 8; ++u) { g[u] = 0.f; fs[u] = 0.f; }
  int j = 0;
  for (; j + 1 < d; j += 2) {
    int jj = r0 + j;
    int s0 = src_s[jj], s1 = src_s[jj + 1];
    float ev0 = ef_s[(size_t)jj * 16 + k4];
    float ev1 = ef_s[(size_t)(jj + 1) * 16 + k4];
    const float4* fp0 = (const float4*)(face + (size_t)s0 * 32 + ib * 8);
    const float4* fp1 = (const float4*)(face + (size_t)s1 * 32 + ib * 8);
    float4 fa0 = fp0[0], fb0 = fp0[1];
    float4 fa1 = fp1[0], fb1 = fp1[1];
    g[0] = fmaf(ev0, fa0.x, g[0]); g[1] = fmaf(ev0, fa0.y, g[1]);
    g[2] = fmaf(ev0, fa0.z, g[2]); g[3] = fmaf(ev0, fa0.w, g[3]);
    g[4] = fmaf(ev0, fb0.x, g[4]); g[5] = fmaf(ev0, fb0.y, g[5]);
    g[6] = fmaf(ev0, fb0.z, g[6]); g[7] = fmaf(ev0, fb0.w, g[7]);
    g[0] = fmaf(ev1, fa1.x, g[0]); g[1] = fmaf(ev1, fa1.y, g[1]);
    g[2] = fmaf(ev1, fa1.z, g[2]); g[3] = fmaf(ev1, fa1.w, g[3]);
    g[4] = fmaf(ev1, fb1.x, g[4]); g[5] = fmaf(ev1, fb1.y, g[5]);
    g[6] = fmaf(ev1, fb1.z, g[6]); g[7] = fmaf(ev1, fb1.w, g[7]);
    if (k4 == 0) {
      fs[0] += fa0.x + fa1.x; fs[1] += fa0.y + fa1.y;
      fs[2] += fa0.z + fa1.z; fs[3] += fa0.w + fa1.w;
      fs[4] += fb0.x + fb1.x; fs[5] += fb0.y + fb1.y;
      fs[6] += fb0.z + fb1.z; fs[7] += fb0.w + fb1.w;
    }
  }
  if (j < d) {
    int jj = r0 + j;
    int s0 = src_s[jj];
    float ev0 = ef_s[(size_t)jj * 16 + k4];
    const float4* fp0 = (const float4*)(face + (size_t)s0 * 32 + ib * 8);
    float4 fa0 = fp0[0], fb0 = fp0[1];
    g[0] = fmaf(ev0, fa0.x, g[0]); g[1] = fmaf(ev0, fa0.y, g[1]);
    g[2] = fmaf(ev0, fa0.z, g[2]); g[3] = fmaf(ev0, fa0.w, g[3]);
    g[4] = fmaf(ev0, fb0.x, g[4]); g[5] = fmaf(ev0, fb0.y, g[5]);
    g[6] = fmaf(ev0, fb0.z, g[6]); g[7] = fmaf(ev0, fb0.w, g[7]);
    if (k4 == 0) {
      fs[0] += fa0.x; fs[1] += fa0.y; fs[2] += fa0.z; fs[3] += fa0.w;
      fs[4] += fb0.x; fs[5] += fb0.y; fs[6] += fb0.z; fs[7] += fb0.w;
    }
  }
  uint4 pv;
  pv.x = pack2(g[0], g[1]); pv.y = pack2(g[2], g[3]);
  pv.z = pack2(g[4], g[5]); pv.w = pack2(g[6], g[7]);
  *(uint4*)(G + (size_t)n * 544 + lane * 8) = pv;
  if (k4 == 0) {
    uint4 fv;
    fv.x = pack2(fs[0], fs[1]); fv.y = pack2(fs[2], fs[3]);
    fv.z = pack2(fs[4], fs[5]); fv.w = pack2(fs[6], fs[7]);
    *(uint4*)(G + (size_t)n * 544 + 512 + ib * 8) = fv;
  }
}

// ---------------- NNConv phase B: sArr = G(NNx544) @ W2bf(544x32), K-chunked GEMM --------
__global__ __launch_bounds__(256, 2) void gemm_G_kernel(const ush* __restrict__ G,
                                                        const ush* __restrict__ W2bf,
                                                        float* __restrict__ sArr, int rows) {
  __shared__ float sA[128][65];
  __shared__ float sW[64][32];
  int t = threadIdx.x;
  int r0 = blockIdx.x * 128;
  int rg = t >> 3, cg = t & 7;
  float acc[4][4];
#pragma unroll
  for (int i = 0; i < 4; ++i)
#pragma unroll
    for (int jc = 0; jc < 4; ++jc) acc[i][jc] = 0.f;
  for (int kc = 0; kc < 9; ++kc) {
    int width = (kc == 8) ? 32 : 64;
    __syncthreads();
    int nv = 128 * (width / 8);
    for (int i = t; i < nv; i += 256) {
      int rr = i / (width / 8), cc = i % (width / 8);
      uint4 v = (r0 + rr < rows)
                    ? *(const uint4*)(G + (size_t)(r0 + rr) * 544 + kc * 64 + cc * 8)
                    : make_uint4(0, 0, 0, 0);
      float* dp = &sA[rr][cc * 8];
      dp[0] = bf2f(v.x & 0xffff); dp[1] = bf2f(v.x >> 16);
      dp[2] = bf2f(v.y & 0xffff); dp[3] = bf2f(v.y >> 16);
      dp[4] = bf2f(v.z & 0xffff); dp[5] = bf2f(v.z >> 16);
      dp[6] = bf2f(v.w & 0xffff); dp[7] = bf2f(v.w >> 16);
    }
    int nw = width * 4;  // width*32/8
    for (int i = t; i < nw; i += 256) {
      int kk = i >> 2, cc = i & 3;
      uint4 v = *(const uint4*)(W2bf + (size_t)(kc * 64 + kk) * 32 + cc * 8);
      float* dp = &sW[kk][cc * 8];
      dp[0] = bf2f(v.x & 0xffff); dp[1] = bf2f(v.x >> 16);
      dp[2] = bf2f(v.y & 0xffff); dp[3] = bf2f(v.y >> 16);
      dp[4] = bf2f(v.z & 0xffff); dp[5] = bf2f(v.z >> 16);
      dp[6] = bf2f(v.w & 0xffff); dp[7] = bf2f(v.w >> 16);
    }
    __syncthreads();
#pragma unroll 8
    for (int k = 0; k < width; ++k) {
      float a0 = sA[rg * 4 + 0][k], a1 = sA[rg * 4 + 1][k];
      float a2 = sA[rg * 4 + 2][k], a3 = sA[rg * 4 + 3][k];
      float4 wv = *(const float4*)&sW[k][cg * 4];
      acc[0][0] = fmaf(a0, wv.x, acc[0][0]); acc[0][1] = fmaf(a0, wv.y, acc[0][1]);
      acc[0][2] = fmaf(a0, wv.z, acc[0][2]); acc[0][3] = fmaf(a0, wv.w, acc[0][3]);
      acc[1][0] = fmaf(a1, wv.x, acc[1][0]); acc[1][1] = fmaf(a1, wv.y, acc[1][1]);
      acc[1][2] = fmaf(a1, wv.z, acc[1][2]); acc[1][3] = fmaf(a1, wv.w, acc[1][3]);
      acc[2][0] = fmaf(a2, wv.x, acc[2][0]); acc[2][1] = fmaf(a2, wv.y, acc[2][1]);
      acc[2][2] = fmaf(a2, wv.z, acc[2][2]); acc[2][3] = fmaf(a2, wv.w, acc[2][3]);
      acc[3][0] = fmaf(a3, wv.x, acc[3][0]); acc[3][1] = fmaf(a3, wv.y, acc[3][1]);
      acc[3][2] = fmaf(a3, wv.z, acc[3][2]); acc[3][3] = fmaf(a3, wv.w, acc[3][3]);
    }
  }
#pragma unroll
  for (int i = 0; i < 4; ++i) {
    int r = r0 + rg * 4 + i;
    if (r < rows)
      *(float4*)(sArr + (size_t)r * 32 + cg * 4) =
          make_float4(acc[i][0], acc[i][1], acc[i][2], acc[i][3]);
  }
}

// ---------------- combine node_features + gate logit (fused; wave per node) --------------
__global__ void combine_gate_kernel(const float* __restrict__ hfin, const float* __restrict__ sArr,
                                    const int* __restrict__ deg, const float* __restrict__ nn_bias,
                                    const float* __restrict__ gate_w, const float* __restrict__ gate_b,
                                    float* __restrict__ out, float* __restrict__ g) {
  int wave = (blockIdx.x * blockDim.x + threadIdx.x) >> 6;
  int lane = threadIdx.x & 63;
  if (wave >= NN) return;
  int n = wave;
  float v0 = hfin[(size_t)n * 64 + lane];
  int c1 = lane + 64;
  float v1 = (c1 < 96)
                 ? sArr[(size_t)n * 32 + (c1 - 64)] / fmaxf((float)deg[n], 1.0f) + nn_bias[c1 - 64]
                 : 0.f;
  out[(size_t)n * 128 + lane] = v0;
  out[(size_t)n * 128 + c1] = v1;
  float p = v0 * gate_w[lane] + ((c1 < 96) ? v1 * gate_w[c1] : 0.f);
#pragma unroll
  for (int off = 32; off; off >>= 1) p += __shfl_xor(p, off, 64);
  if (lane == 0) g[n] = p + gate_b[0];
}

// ---------------- max over g (block-reduced, 1 atomic per block) ----------------
__global__ void gate_max_kernel(const float* __restrict__ g, unsigned* __restrict__ gmax) {
  int tid = blockIdx.x * blockDim.x + threadIdx.x;
  int stride = gridDim.x * blockDim.x;
  float v = -3.0e38f;
  for (int n = tid; n < NN; n += stride) v = fmaxf(v, g[n]);
#pragma unroll
  for (int off = 32; off; off >>= 1) v = fmaxf(v, __shfl_xor(v, off, 64));
  __shared__ float sm[4];
  int lane = threadIdx.x & 63, wid = threadIdx.x >> 6;
  if (lane == 0) sm[wid] = v;
  __syncthreads();
  if (threadIdx.x == 0) {
    float m = fmaxf(fmaxf(sm[0], sm[1]), fmaxf(sm[2], sm[3]));
    atomicMax(gmax, ord_enc(m));
  }
}

// ---------------- pooling: exp + weighted accumulate (fused) ----------------
__global__ void pool_exp_kernel(const float* __restrict__ nf, const float* __restrict__ g,
                                const unsigned* __restrict__ gmax, float* __restrict__ gacc,
                                float* __restrict__ gsum) {
  int o = threadIdx.x;  // blockDim = 128
  float m = ord_dec(*gmax);
  float acc = 0.f, ws = 0.f;
  for (int n = blockIdx.x; n < NN; n += gridDim.x) {
    float w = __expf(g[n] - m);
    ws += w;
    acc += w * nf[(size_t)n * 128 + o];
  }
  atomicAdd(gacc + o, acc);
  if (o == 0) atomicAdd(gsum, ws);
}

__global__ void finalize_kernel(const float* __restrict__ gacc, const float* __restrict__ gsum,
                                float* __restrict__ out) {
  int o = threadIdx.x;
  if (o < 128) out[(size_t)NN * 128 + o] = gacc[o] / gsum[0];
}

extern "C" void kernel_launch(void* const* d_in, const int* in_sizes, int n_in,
                              void* d_out, int out_size, void* d_ws, size_t ws_size,
                              hipStream_t stream) {
  const float* face    = (const float*)d_in[0];
  const float* ef      = (const float*)d_in[1];
  const float* fp_w    = (const float*)d_in[2];
  const float* fp_b    = (const float*)d_in[3];
  const float* ep_w    = (const float*)d_in[4];
  const float* ep_b    = (const float*)d_in[5];
  const float* nn_w    = (const float*)d_in[6];
  const float* nn_b    = (const float*)d_in[7];
  const float* nn_bias = (const float*)d_in[8];
  const float* gate_w  = (const float*)d_in[9];
  const float* gate_b  = (const float*)d_in[10];
  const int*   src     = (const int*)d_in[11];
  const int*   dst     = (const int*)d_in[12];
  const float* e1_attn = (const float*)d_in[17];
  const float* e2_ni   = (const float*)d_in[19];
  const float* e2_nj   = (const float*)d_in[20];
  const float* e2_fij  = (const float*)d_in[21];
  const float* e2_node = (const float*)d_in[22];
  const float* e2_attn = (const float*)d_in[23];
  const float* e2_bias = (const float*)d_in[24];
  float* out = (float*)d_out;

  char* p = (char*)d_ws;
  auto alloc = [&](size_t nfloats) {
    float* r = (float*)p;
    p += ((nfloats * 4 + 255) / 256) * 256;
    return r;
  };
  float* h0 = alloc((size_t)NN * 64);   // layer-2 output
  float* h1 = alloc((size_t)NN * 64);   // layer-1 output
  // big region: G (NN*544 bf16 = 65.28 MB) aliases hs16|hd16|hn16|f116|logit (dead post-EGAT)
  char* bigreg = p;
  ush* hs16 = (ush*)alloc((size_t)NN * 32);   // NN*64 bf16
  ush* hd16 = (ush*)alloc((size_t)NN * 32);
  ush* hn16 = (ush*)alloc((size_t)NN * 32);
  ush* f116 = (ush*)alloc((size_t)NE * 32);   // NE*64 bf16 (dst-sorted order)
  float* logit = alloc(NE);                   // dst-sorted order
  {  // pad bigreg to >= NN*544*2 bytes for G
    size_t used = (size_t)(p - bigreg);
    size_t need = (size_t)NN * 544 * 2;
    if (used < need) p += ((need - used + 255) / 256) * 256;
  }
  ush* G = (ush*)bigreg;
  float* sArr  = alloc((size_t)NN * 32);
  float* g     = alloc(NN);
  float* gacc  = alloc(128);
  float* gsum  = alloc(1);
  unsigned* gmax = (unsigned*)alloc(1);
  float* fold  = alloc(7424);
  ush* W2bf    = (ush*)alloc(544 * 16);       // 544*32 bf16
  // dst-CSR
  int* deg    = (int*)alloc(NN);
  int* rowptr = (int*)alloc(NN);
  int* cursor = (int*)alloc(NN);
  int* partial = (int*)alloc(256);
  int* src_s  = (int*)alloc(NE);
  int* dst_s  = (int*)alloc(NE);
  float* ef_s = alloc((size_t)NE * 16);       // permuted edge features

  const float* Wf1  = fold;
  const float* b1f  = fold + 1024;
  const float* Wni1 = fold + 1088;
  const float* Wnj1 = fold + 3136;
  const float* Wno1 = fold + 5184;
  const float* bni1 = fold + 7232;
  const float* bnj1 = fold + 7296;
  const float* bno1 = fold + 7360;

  const int B = 256;
  const int NGB = cdiv(NN, 128);
  const int EGB = cdiv(NE, 128);
  const int NB256 = cdiv(NN, 256);

  // ---- CSR build (dst-sorted) + fused edge permutation ----
  hipMemsetAsync(deg, 0, NN * 4, stream);
  deg_kernel<<<cdiv(NE, B), B, 0, stream>>>(dst, deg);
  scan1_kernel<<<NB256, 256, 0, stream>>>(deg, rowptr, partial);
  scan2_kernel<<<1, 256, 0, stream>>>(partial, NB256);
  scan3_kernel<<<NB256, 256, 0, stream>>>(rowptr, partial, cursor);
  scatter_dst_kernel<<<cdiv(NE, B), B, 0, stream>>>(src, dst, ef, cursor, src_s, dst_s, ef_s);

  // folded weights + nn weight pack (tiny)
  fold_kernel<<<29, B, 0, stream>>>(fp_w, fp_b, ep_w, ep_b,
                                    (const float*)d_in[15], (const float*)d_in[18],
                                    (const float*)d_in[13], (const float*)d_in[14],
                                    (const float*)d_in[16], fold);
  nnwt_kernel<<<68, B, 0, stream>>>(nn_w, nn_b, W2bf);

  // ---- EGAT layer 1 (edges processed in dst-sorted order) ----
  gemm3_kernel<32, true><<<dim3(NGB, 3), B, 0, stream>>>(face, Wni1, Wnj1, Wno1, bni1, bnj1,
                                                         bno1, hs16, hd16, hn16, NN);
  gemm_fout_kernel<16, true, false><<<EGB, B, 0, stream>>>(ef_s, Wf1, b1f, hs16, hd16, src_s,
                                                           dst_s, e1_attn, f116, logit);
  agg_gather_kernel<<<cdiv(NN * 64, B), B, 0, stream>>>(hn16, logit, rowptr, deg, src_s, h1);

  // ---- EGAT layer 2 ----
  gemm3_kernel<64, false><<<dim3(NGB, 3), B, 0, stream>>>(h1, e2_ni, e2_nj, e2_node, nullptr,
                                                          nullptr, nullptr, hs16, hd16, hn16, NN);
  gemm_fout_kernel<64, false, true><<<EGB, B, 0, stream>>>(f116, e2_fij, e2_bias, hs16, hd16,
                                                           src_s, dst_s, e2_attn, nullptr, logit);
  agg_gather_kernel<<<cdiv(NN * 64, B), B, 0, stream>>>(hn16, logit, rowptr, deg, src_s, h0);

  // ---- NNConv (outer-product form; G aliases dead EGAT buffers — runs after EGAT) ----
  nnconv_G_kernel<<<cdiv(NN * 64, B), B, 0, stream>>>(face, ef_s, rowptr, deg, src_s, G);
  gemm_G_kernel<<<NGB, B, 0, stream>>>(G, W2bf, sArr, NN);

  // ---- combine node features + gate logits ----
  hipMemsetAsync(gacc, 0, 128 * 4, stream);
  hipMemsetAsync(gsum, 0, 4, stream);
  hipMemsetAsync(gmax, 0, 4, stream);
  combine_gate_kernel<<<cdiv(NN * 64, B), B, 0, stream>>>(h0, sArr, deg, nn_bias, gate_w,
                                                          gate_b, out, g);
  gate_max_kernel<<<128, B, 0, stream>>>(g, gmax);
  pool_exp_kernel<<<512, 128, 0, stream>>>(out, g, gmax, gacc, gsum);
  finalize_kernel<<<1, 128, 0, stream>>>(gacc, gsum, out);
}